// Round 1
// baseline (755.238 us; speedup 1.0000x reference)
//
#include <hip/hip_runtime.h>

#define TT 1024
#define DD 1024
#define BB 8
#define FF 4096
#define MM (BB * TT)

typedef unsigned short u16;
typedef unsigned int u32;

typedef __attribute__((ext_vector_type(8))) short short8;
typedef __attribute__((ext_vector_type(4))) float floatx4;

__device__ __forceinline__ u16 f2bf(float f) {
  u32 u = __float_as_uint(f);
  u32 r = (u + 0x7fffu + ((u >> 16) & 1u)) >> 16;
  return (u16)r;
}
__device__ __forceinline__ float bf2f(u16 h) { return __uint_as_float(((u32)h) << 16); }
__device__ __forceinline__ float sigmoidf_(float v) { return 1.0f / (1.0f + __expf(-v)); }

// ---------------- weight transpose fp32[K,N] -> bf16[N,K] ----------------
__global__ void transpose_bf16(const float* __restrict__ in, u16* __restrict__ out, int K, int N) {
  __shared__ float tile[32][33];
  int tx = threadIdx.x, ty = threadIdx.y;
  int n0 = blockIdx.x * 32, k0 = blockIdx.y * 32;
#pragma unroll
  for (int j = 0; j < 32; j += 8)
    tile[ty + j][tx] = in[(size_t)(k0 + ty + j) * N + (n0 + tx)];
  __syncthreads();
#pragma unroll
  for (int j = 0; j < 32; j += 8)
    out[(size_t)(n0 + ty + j) * K + (k0 + tx)] = f2bf(tile[tx][ty + j]);
}

// ---------------- LN1 + token shift + 3 mixes -> bf16 ----------------
__global__ void ln1mix_kernel(const float* __restrict__ x, const float* __restrict__ attx,
                              const float* __restrict__ g, const float* __restrict__ be,
                              const float* __restrict__ mk, const float* __restrict__ mv,
                              const float* __restrict__ mr,
                              u16* __restrict__ xk, u16* __restrict__ xv, u16* __restrict__ xr,
                              float* __restrict__ xn_last) {
  int row = blockIdx.x, tid = threadIdx.x;
  int b = row >> 10, t = row & (TT - 1);
  float4 xc = ((const float4*)(x + (size_t)row * DD))[tid];
  float4 xp = (t == 0) ? ((const float4*)(attx + (size_t)b * DD))[tid]
                       : ((const float4*)(x + (size_t)(row - 1) * DD))[tid];
  float sc = xc.x + xc.y + xc.z + xc.w;
  float qc = xc.x * xc.x + xc.y * xc.y + xc.z * xc.z + xc.w * xc.w;
  float sp = xp.x + xp.y + xp.z + xp.w;
  float qp = xp.x * xp.x + xp.y * xp.y + xp.z * xp.z + xp.w * xp.w;
#pragma unroll
  for (int o = 32; o > 0; o >>= 1) {
    sc += __shfl_xor(sc, o); qc += __shfl_xor(qc, o);
    sp += __shfl_xor(sp, o); qp += __shfl_xor(qp, o);
  }
  __shared__ float red[4][4];
  int lane = tid & 63, wid = tid >> 6;
  if (lane == 0) { red[wid][0] = sc; red[wid][1] = qc; red[wid][2] = sp; red[wid][3] = qp; }
  __syncthreads();
  sc = red[0][0] + red[1][0] + red[2][0] + red[3][0];
  qc = red[0][1] + red[1][1] + red[2][1] + red[3][1];
  sp = red[0][2] + red[1][2] + red[2][2] + red[3][2];
  qp = red[0][3] + red[1][3] + red[2][3] + red[3][3];
  const float inv = 1.0f / (float)DD;
  float muc = sc * inv, varc = qc * inv - muc * muc;
  float rc = rsqrtf(varc + 1e-3f);
  float mup = sp * inv, varp = qp * inv - mup * mup;
  float rp = rsqrtf(varp + 1e-3f);
  float4 gg = ((const float4*)g)[tid];
  float4 bb = ((const float4*)be)[tid];
  float4 k4 = ((const float4*)mk)[tid];
  float4 v4 = ((const float4*)mv)[tid];
  float4 r4 = ((const float4*)mr)[tid];
  float xcv[4] = {xc.x, xc.y, xc.z, xc.w};
  float xpv[4] = {xp.x, xp.y, xp.z, xp.w};
  float gv[4] = {gg.x, gg.y, gg.z, gg.w};
  float bv[4] = {bb.x, bb.y, bb.z, bb.w};
  float kv[4] = {k4.x, k4.y, k4.z, k4.w};
  float vv[4] = {v4.x, v4.y, v4.z, v4.w};
  float rv[4] = {r4.x, r4.y, r4.z, r4.w};
  u16 ok[4], ov[4], orr[4];
  float nc[4];
#pragma unroll
  for (int i = 0; i < 4; i++) {
    nc[i] = (xcv[i] - muc) * rc * gv[i] + bv[i];
    float np = (t == 0) ? xpv[i] : ((xpv[i] - mup) * rp * gv[i] + bv[i]);
    ok[i] = f2bf(nc[i] * kv[i] + np * (1.0f - kv[i]));
    ov[i] = f2bf(nc[i] * vv[i] + np * (1.0f - vv[i]));
    orr[i] = f2bf(nc[i] * rv[i] + np * (1.0f - rv[i]));
  }
  size_t o4 = (size_t)row * (DD / 4) + tid;
  ((ushort4*)xk)[o4] = make_ushort4(ok[0], ok[1], ok[2], ok[3]);
  ((ushort4*)xv)[o4] = make_ushort4(ov[0], ov[1], ov[2], ov[3]);
  ((ushort4*)xr)[o4] = make_ushort4(orr[0], orr[1], orr[2], orr[3]);
  if (t == TT - 1)
    ((float4*)xn_last)[(size_t)b * (DD / 4) + tid] = make_float4(nc[0], nc[1], nc[2], nc[3]);
}

// ---------------- LN2 + token shift + 2 mixes -> bf16 ----------------
__global__ void ln2mix_kernel(const float* __restrict__ x1, const float* __restrict__ ffnx,
                              const float* __restrict__ g, const float* __restrict__ be,
                              const float* __restrict__ cmk, const float* __restrict__ cmr,
                              u16* __restrict__ xk2, u16* __restrict__ xr2,
                              float* __restrict__ xn2_last) {
  int row = blockIdx.x, tid = threadIdx.x;
  int b = row >> 10, t = row & (TT - 1);
  float4 xc = ((const float4*)(x1 + (size_t)row * DD))[tid];
  float4 xp = (t == 0) ? ((const float4*)(ffnx + (size_t)b * DD))[tid]
                       : ((const float4*)(x1 + (size_t)(row - 1) * DD))[tid];
  float sc = xc.x + xc.y + xc.z + xc.w;
  float qc = xc.x * xc.x + xc.y * xc.y + xc.z * xc.z + xc.w * xc.w;
  float sp = xp.x + xp.y + xp.z + xp.w;
  float qp = xp.x * xp.x + xp.y * xp.y + xp.z * xp.z + xp.w * xp.w;
#pragma unroll
  for (int o = 32; o > 0; o >>= 1) {
    sc += __shfl_xor(sc, o); qc += __shfl_xor(qc, o);
    sp += __shfl_xor(sp, o); qp += __shfl_xor(qp, o);
  }
  __shared__ float red[4][4];
  int lane = tid & 63, wid = tid >> 6;
  if (lane == 0) { red[wid][0] = sc; red[wid][1] = qc; red[wid][2] = sp; red[wid][3] = qp; }
  __syncthreads();
  sc = red[0][0] + red[1][0] + red[2][0] + red[3][0];
  qc = red[0][1] + red[1][1] + red[2][1] + red[3][1];
  sp = red[0][2] + red[1][2] + red[2][2] + red[3][2];
  qp = red[0][3] + red[1][3] + red[2][3] + red[3][3];
  const float inv = 1.0f / (float)DD;
  float muc = sc * inv, varc = qc * inv - muc * muc;
  float rc = rsqrtf(varc + 1e-3f);
  float mup = sp * inv, varp = qp * inv - mup * mup;
  float rp = rsqrtf(varp + 1e-3f);
  float4 gg = ((const float4*)g)[tid];
  float4 bb = ((const float4*)be)[tid];
  float4 k4 = ((const float4*)cmk)[tid];
  float4 r4 = ((const float4*)cmr)[tid];
  float xcv[4] = {xc.x, xc.y, xc.z, xc.w};
  float xpv[4] = {xp.x, xp.y, xp.z, xp.w};
  float gv[4] = {gg.x, gg.y, gg.z, gg.w};
  float bv[4] = {bb.x, bb.y, bb.z, bb.w};
  float kv[4] = {k4.x, k4.y, k4.z, k4.w};
  float rv[4] = {r4.x, r4.y, r4.z, r4.w};
  u16 ok[4], orr[4];
  float nc[4];
#pragma unroll
  for (int i = 0; i < 4; i++) {
    nc[i] = (xcv[i] - muc) * rc * gv[i] + bv[i];
    float np = (t == 0) ? xpv[i] : ((xpv[i] - mup) * rp * gv[i] + bv[i]);
    ok[i] = f2bf(nc[i] * kv[i] + np * (1.0f - kv[i]));
    orr[i] = f2bf(nc[i] * rv[i] + np * (1.0f - rv[i]));
  }
  size_t o4 = (size_t)row * (DD / 4) + tid;
  ((ushort4*)xk2)[o4] = make_ushort4(ok[0], ok[1], ok[2], ok[3]);
  ((ushort4*)xr2)[o4] = make_ushort4(orr[0], orr[1], orr[2], orr[3]);
  if (t == TT - 1)
    ((float4*)xn2_last)[(size_t)b * (DD / 4) + tid] = make_float4(nc[0], nc[1], nc[2], nc[3]);
}

// ---------------- rm = bf16( sigmoid(r) * wkv ) ----------------
__global__ void rmul_kernel(const u16* __restrict__ sr, const float* __restrict__ wk,
                            u16* __restrict__ rm) {
  size_t i = (size_t)blockIdx.x * blockDim.x + threadIdx.x;
  float4 wv = ((const float4*)wk)[i];
  ushort4 s = ((const ushort4*)sr)[i];
  ushort4 o;
  o.x = f2bf(bf2f(s.x) * wv.x);
  o.y = f2bf(bf2f(s.y) * wv.y);
  o.z = f2bf(bf2f(s.z) * wv.z);
  o.w = f2bf(bf2f(s.w) * wv.w);
  ((ushort4*)rm)[i] = o;
}

// ---------------- WKV scan (1 thread / channel, reg double-buffer) ----------------
__device__ __forceinline__ void wkv_load16(const float* kp, const float* vp, int t0,
                                           float (&kk)[16], float (&vv)[16]) {
#pragma unroll
  for (int j = 0; j < 16; j++) {
    kk[j] = kp[(size_t)(t0 + j) * DD];
    vv[j] = vp[(size_t)(t0 + j) * DD];
  }
}
__device__ __forceinline__ void wkv_comp16(const float (&kk)[16], const float (&vv)[16], int t0,
                                           float* op, float& aa, float& bb, float& pp,
                                           float w, float u) {
#pragma unroll
  for (int j = 0; j < 16; j++) {
    float kt = kk[j], vt = vv[j];
    float ww = u + kt;
    float p = fmaxf(pp, ww);
    float e1 = __expf(pp - p);
    float e2 = __expf(ww - p);
    float num = e1 * aa + e2 * vt;
    float den = e1 * bb + e2;
    op[(size_t)(t0 + j) * DD] = __fdividef(num, den);
    float ww2 = pp + w;
    float p2 = fmaxf(ww2, kt);
    float e1b = __expf(ww2 - p2);
    float e2b = __expf(kt - p2);
    aa = e1b * aa + e2b * vt;
    bb = e1b * bb + e2b;
    pp = p2;
  }
}

__global__ void wkv_scan_kernel(const float* __restrict__ K, const float* __restrict__ V,
                                const float* __restrict__ decay, const float* __restrict__ first,
                                const float* __restrict__ aa0, const float* __restrict__ bb0,
                                const float* __restrict__ pp0, float* __restrict__ wkv,
                                float* __restrict__ aa_out, float* __restrict__ bb_out,
                                float* __restrict__ pp_out) {
  int gid = blockIdx.x * 64 + threadIdx.x;  // 0..B*D-1
  int b = gid >> 10, d = gid & (DD - 1);
  float w = -__expf(decay[d]);
  float u = first[d];
  float aa = aa0[gid], bb = bb0[gid], pp = pp0[gid];
  const float* kp = K + (size_t)b * TT * DD + d;
  const float* vp = V + (size_t)b * TT * DD + d;
  float* op = wkv + (size_t)b * TT * DD + d;
  float ka[16], va[16], kb2[16], vb2[16];
  wkv_load16(kp, vp, 0, ka, va);
  for (int c = 0; c < TT / 16; c += 2) {
    wkv_load16(kp, vp, (c + 1) * 16, kb2, vb2);
    wkv_comp16(ka, va, c * 16, op, aa, bb, pp, w, u);
    if (c + 2 < TT / 16) wkv_load16(kp, vp, (c + 2) * 16, ka, va);
    wkv_comp16(kb2, vb2, (c + 1) * 16, op, aa, bb, pp, w, u);
  }
  aa_out[gid] = aa;
  bb_out[gid] = bb;
  pp_out[gid] = pp;
}

// ---------------- bf16 MFMA GEMM, C = A[M,K] @ B (BT given as [N,K]) ----------------
// MODE 0: C fp32 = A@B
// MODE 1: C bf16 = sigmoid(A@B)
// MODE 2: C bf16 = relu(A@B)^2
// MODE 3: C fp32 = A@B + R1
// MODE 4: C fp32 = R1 + bf2f(R2) * (A@B)
#define LDSP 40

template <int MODE>
__global__ void gemm_bt(const u16* __restrict__ A, const u16* __restrict__ BT,
                        const float* R1, const u16* R2, void* Cout, int M, int N, int K) {
  __shared__ u16 lA[128 * LDSP];
  __shared__ u16 lB[128 * LDSP];
  int tid = threadIdx.x;
  int lane = tid & 63;
  int wid = tid >> 6;
  int wy = wid >> 1, wx = wid & 1;
  int m0 = blockIdx.y * 128, n0 = blockIdx.x * 128;
  int rlo = lane & 15, koff = (lane >> 4) * 8;
  int r0 = tid >> 2, c0 = (tid & 3) * 8;
  floatx4 acc[4][4];
#pragma unroll
  for (int mi = 0; mi < 4; mi++)
#pragma unroll
    for (int ni = 0; ni < 4; ni++)
#pragma unroll
      for (int e = 0; e < 4; e++) acc[mi][ni][e] = 0.0f;

  const u16* Arow0 = A + (size_t)(m0 + r0) * K + c0;
  const u16* Arow1 = A + (size_t)(m0 + r0 + 64) * K + c0;
  const u16* Brow0 = BT + (size_t)(n0 + r0) * K + c0;
  const u16* Brow1 = BT + (size_t)(n0 + r0 + 64) * K + c0;

  for (int kt = 0; kt < K; kt += 32) {
    __syncthreads();
    *(uint4*)&lA[r0 * LDSP + c0] = *(const uint4*)(Arow0 + kt);
    *(uint4*)&lA[(r0 + 64) * LDSP + c0] = *(const uint4*)(Arow1 + kt);
    *(uint4*)&lB[r0 * LDSP + c0] = *(const uint4*)(Brow0 + kt);
    *(uint4*)&lB[(r0 + 64) * LDSP + c0] = *(const uint4*)(Brow1 + kt);
    __syncthreads();
    short8 af[4], bfr[4];
#pragma unroll
    for (int mi = 0; mi < 4; mi++)
      af[mi] = *(const short8*)&lA[(wy * 64 + mi * 16 + rlo) * LDSP + koff];
#pragma unroll
    for (int ni = 0; ni < 4; ni++)
      bfr[ni] = *(const short8*)&lB[(wx * 64 + ni * 16 + rlo) * LDSP + koff];
#pragma unroll
    for (int mi = 0; mi < 4; mi++)
#pragma unroll
      for (int ni = 0; ni < 4; ni++)
        acc[mi][ni] = __builtin_amdgcn_mfma_f32_16x16x32_bf16(af[mi], bfr[ni], acc[mi][ni], 0, 0, 0);
  }

  int rbase = (lane >> 4) * 4;
#pragma unroll
  for (int mi = 0; mi < 4; mi++) {
#pragma unroll
    for (int ni = 0; ni < 4; ni++) {
#pragma unroll
      for (int r = 0; r < 4; r++) {
        int row = m0 + wy * 64 + mi * 16 + rbase + r;
        int col = n0 + wx * 64 + ni * 16 + rlo;
        size_t idx = (size_t)row * N + col;
        float v = acc[mi][ni][r];
        if (MODE == 0) {
          ((float*)Cout)[idx] = v;
        } else if (MODE == 1) {
          ((u16*)Cout)[idx] = f2bf(sigmoidf_(v));
        } else if (MODE == 2) {
          float tpos = fmaxf(v, 0.0f);
          ((u16*)Cout)[idx] = f2bf(tpos * tpos);
        } else if (MODE == 3) {
          ((float*)Cout)[idx] = v + R1[idx];
        } else {
          ((float*)Cout)[idx] = R1[idx] + bf2f(R2[idx]) * v;
        }
      }
    }
  }
}

extern "C" void kernel_launch(void* const* d_in, const int* in_sizes, int n_in,
                              void* d_out, int out_size, void* d_ws, size_t ws_size,
                              hipStream_t stream) {
  const float* x    = (const float*)d_in[0];
  const float* attx = (const float*)d_in[1];
  const float* aa0  = (const float*)d_in[2];
  const float* bb0  = (const float*)d_in[3];
  const float* pp0  = (const float*)d_in[4];
  const float* ffnx = (const float*)d_in[5];
  const float* ln1g = (const float*)d_in[6];
  const float* ln1b = (const float*)d_in[7];
  const float* ln2g = (const float*)d_in[8];
  const float* ln2b = (const float*)d_in[9];
  const float* mk   = (const float*)d_in[10];
  const float* mv   = (const float*)d_in[11];
  const float* mr   = (const float*)d_in[12];
  const float* decay= (const float*)d_in[13];
  const float* first= (const float*)d_in[14];
  const float* Wk   = (const float*)d_in[15];
  const float* Wv   = (const float*)d_in[16];
  const float* Wr   = (const float*)d_in[17];
  const float* Wo   = (const float*)d_in[18];
  const float* cmk  = (const float*)d_in[19];
  const float* cmr  = (const float*)d_in[20];
  const float* Ck   = (const float*)d_in[21];
  const float* Cr   = (const float*)d_in[22];
  const float* Cv   = (const float*)d_in[23];

  float* out      = (float*)d_out;
  float* xn_last  = out + (size_t)BB * TT * DD;
  float* aa_out   = xn_last + BB * DD;
  float* bb_out   = aa_out + BB * DD;
  float* pp_out   = bb_out + BB * DD;
  float* xn2_last = pp_out + BB * DD;
  float* x1 = out;  // x1 lives in the out buffer (safe: final epilogue reads R1[idx] then writes same idx)

  char* ws = (char*)d_ws;
  const size_t MB = 1024ull * 1024ull;
  u16* WkT   = (u16*)(ws + 0 * MB);     // 2MB
  u16* WvT   = (u16*)(ws + 2 * MB);
  u16* WrT   = (u16*)(ws + 4 * MB);
  u16* WoT   = (u16*)(ws + 6 * MB);
  u16* CrT   = (u16*)(ws + 8 * MB);
  u16* CkT   = (u16*)(ws + 10 * MB);    // 8MB  [4096,1024]
  u16* CvT   = (u16*)(ws + 18 * MB);    // 8MB  [1024,4096]
  u16* xk    = (u16*)(ws + 26 * MB);    // 16MB
  u16* xv    = (u16*)(ws + 42 * MB);    // 16MB
  u16* xr    = (u16*)(ws + 58 * MB);    // 16MB
  float* kbuf= (float*)(ws + 74 * MB);  // 32MB
  float* vbuf= (float*)(ws + 106 * MB); // 32MB
  u16* sigr  = (u16*)(ws + 138 * MB);   // 16MB
  float* wkvb= (float*)(ws + 154 * MB); // 32MB -> peak 186MB
  // reuse (lifetimes disjoint):
  u16* rmb   = (u16*)(ws + 26 * MB);    // over xk (dead after Wk GEMM)
  u16* xk2   = (u16*)(ws + 26 * MB);    // over rmb (dead after Wo GEMM)
  u16* xr2   = (u16*)(ws + 42 * MB);    // over xv
  u16* sigr2 = (u16*)(ws + 58 * MB);    // over xr
  u16* kc    = (u16*)(ws + 74 * MB);    // 64MB over kbuf+vbuf (dead after scan)

  dim3 tb32(32, 8);
  transpose_bf16<<<dim3(32, 32), tb32, 0, stream>>>(Wk, WkT, 1024, 1024);
  transpose_bf16<<<dim3(32, 32), tb32, 0, stream>>>(Wv, WvT, 1024, 1024);
  transpose_bf16<<<dim3(32, 32), tb32, 0, stream>>>(Wr, WrT, 1024, 1024);
  transpose_bf16<<<dim3(32, 32), tb32, 0, stream>>>(Wo, WoT, 1024, 1024);
  transpose_bf16<<<dim3(32, 32), tb32, 0, stream>>>(Cr, CrT, 1024, 1024);
  transpose_bf16<<<dim3(128, 32), tb32, 0, stream>>>(Ck, CkT, 1024, 4096);
  transpose_bf16<<<dim3(32, 128), tb32, 0, stream>>>(Cv, CvT, 4096, 1024);

  ln1mix_kernel<<<MM, 256, 0, stream>>>(x, attx, ln1g, ln1b, mk, mv, mr, xk, xv, xr, xn_last);

  gemm_bt<0><<<dim3(8, 64), 256, 0, stream>>>(xk, WkT, nullptr, nullptr, kbuf, MM, 1024, 1024);
  gemm_bt<0><<<dim3(8, 64), 256, 0, stream>>>(xv, WvT, nullptr, nullptr, vbuf, MM, 1024, 1024);
  gemm_bt<1><<<dim3(8, 64), 256, 0, stream>>>(xr, WrT, nullptr, nullptr, sigr, MM, 1024, 1024);

  wkv_scan_kernel<<<128, 64, 0, stream>>>(kbuf, vbuf, decay, first, aa0, bb0, pp0, wkvb,
                                          aa_out, bb_out, pp_out);

  rmul_kernel<<<MM, 256, 0, stream>>>(sigr, wkvb, rmb);

  gemm_bt<3><<<dim3(8, 64), 256, 0, stream>>>(rmb, WoT, x, nullptr, x1, MM, 1024, 1024);

  ln2mix_kernel<<<MM, 256, 0, stream>>>(x1, ffnx, ln2g, ln2b, cmk, cmr, xk2, xr2, xn2_last);

  gemm_bt<2><<<dim3(32, 64), 256, 0, stream>>>(xk2, CkT, nullptr, nullptr, kc, MM, 4096, 1024);
  gemm_bt<1><<<dim3(8, 64), 256, 0, stream>>>(xr2, CrT, nullptr, nullptr, sigr2, MM, 1024, 1024);
  gemm_bt<4><<<dim3(8, 64), 256, 0, stream>>>(kc, CvT, x1, sigr2, out, MM, 1024, 4096);
}

// Round 2
// 576.349 us; speedup vs baseline: 1.3104x; 1.3104x over previous
//
#include <hip/hip_runtime.h>

#define TT 1024
#define DD 1024
#define BB 8
#define FF 4096
#define MM (BB * TT)
#define CHL 32                 // WKV chunk length
#define NCH (TT / CHL)         // 32 chunks
#define NCHAN (BB * DD)        // 8192 channels

typedef unsigned short u16;
typedef unsigned int u32;

typedef __attribute__((ext_vector_type(8))) short short8;
typedef __attribute__((ext_vector_type(4))) float floatx4;

__device__ __forceinline__ u16 f2bf(float f) {
  u32 u = __float_as_uint(f);
  u32 r = (u + 0x7fffu + ((u >> 16) & 1u)) >> 16;
  return (u16)r;
}
__device__ __forceinline__ float bf2f(u16 h) { return __uint_as_float(((u32)h) << 16); }
__device__ __forceinline__ float sigmoidf_(float v) { return 1.0f / (1.0f + __expf(-v)); }

// ---------------- weight transpose fp32[K,N] -> bf16[N,K] ----------------
__global__ void transpose_bf16(const float* __restrict__ in, u16* __restrict__ out, int K, int N) {
  __shared__ float tile[32][33];
  int tx = threadIdx.x, ty = threadIdx.y;
  int n0 = blockIdx.x * 32, k0 = blockIdx.y * 32;
#pragma unroll
  for (int j = 0; j < 32; j += 8)
    tile[ty + j][tx] = in[(size_t)(k0 + ty + j) * N + (n0 + tx)];
  __syncthreads();
#pragma unroll
  for (int j = 0; j < 32; j += 8)
    out[(size_t)(n0 + ty + j) * K + (k0 + tx)] = f2bf(tile[tx][ty + j]);
}

// ---------------- LN1 + token shift + 3 mixes -> bf16 ----------------
__global__ void ln1mix_kernel(const float* __restrict__ x, const float* __restrict__ attx,
                              const float* __restrict__ g, const float* __restrict__ be,
                              const float* __restrict__ mk, const float* __restrict__ mv,
                              const float* __restrict__ mr,
                              u16* __restrict__ xk, u16* __restrict__ xv, u16* __restrict__ xr,
                              float* __restrict__ xn_last) {
  int row = blockIdx.x, tid = threadIdx.x;
  int b = row >> 10, t = row & (TT - 1);
  float4 xc = ((const float4*)(x + (size_t)row * DD))[tid];
  float4 xp = (t == 0) ? ((const float4*)(attx + (size_t)b * DD))[tid]
                       : ((const float4*)(x + (size_t)(row - 1) * DD))[tid];
  float sc = xc.x + xc.y + xc.z + xc.w;
  float qc = xc.x * xc.x + xc.y * xc.y + xc.z * xc.z + xc.w * xc.w;
  float sp = xp.x + xp.y + xp.z + xp.w;
  float qp = xp.x * xp.x + xp.y * xp.y + xp.z * xp.z + xp.w * xp.w;
#pragma unroll
  for (int o = 32; o > 0; o >>= 1) {
    sc += __shfl_xor(sc, o); qc += __shfl_xor(qc, o);
    sp += __shfl_xor(sp, o); qp += __shfl_xor(qp, o);
  }
  __shared__ float red[4][4];
  int lane = tid & 63, wid = tid >> 6;
  if (lane == 0) { red[wid][0] = sc; red[wid][1] = qc; red[wid][2] = sp; red[wid][3] = qp; }
  __syncthreads();
  sc = red[0][0] + red[1][0] + red[2][0] + red[3][0];
  qc = red[0][1] + red[1][1] + red[2][1] + red[3][1];
  sp = red[0][2] + red[1][2] + red[2][2] + red[3][2];
  qp = red[0][3] + red[1][3] + red[2][3] + red[3][3];
  const float inv = 1.0f / (float)DD;
  float muc = sc * inv, varc = qc * inv - muc * muc;
  float rc = rsqrtf(varc + 1e-3f);
  float mup = sp * inv, varp = qp * inv - mup * mup;
  float rp = rsqrtf(varp + 1e-3f);
  float4 gg = ((const float4*)g)[tid];
  float4 bb = ((const float4*)be)[tid];
  float4 k4 = ((const float4*)mk)[tid];
  float4 v4 = ((const float4*)mv)[tid];
  float4 r4 = ((const float4*)mr)[tid];
  float xcv[4] = {xc.x, xc.y, xc.z, xc.w};
  float xpv[4] = {xp.x, xp.y, xp.z, xp.w};
  float gv[4] = {gg.x, gg.y, gg.z, gg.w};
  float bv[4] = {bb.x, bb.y, bb.z, bb.w};
  float kv[4] = {k4.x, k4.y, k4.z, k4.w};
  float vv[4] = {v4.x, v4.y, v4.z, v4.w};
  float rv[4] = {r4.x, r4.y, r4.z, r4.w};
  u16 ok[4], ov[4], orr[4];
  float nc[4];
#pragma unroll
  for (int i = 0; i < 4; i++) {
    nc[i] = (xcv[i] - muc) * rc * gv[i] + bv[i];
    float np = (t == 0) ? xpv[i] : ((xpv[i] - mup) * rp * gv[i] + bv[i]);
    ok[i] = f2bf(nc[i] * kv[i] + np * (1.0f - kv[i]));
    ov[i] = f2bf(nc[i] * vv[i] + np * (1.0f - vv[i]));
    orr[i] = f2bf(nc[i] * rv[i] + np * (1.0f - rv[i]));
  }
  size_t o4 = (size_t)row * (DD / 4) + tid;
  ((ushort4*)xk)[o4] = make_ushort4(ok[0], ok[1], ok[2], ok[3]);
  ((ushort4*)xv)[o4] = make_ushort4(ov[0], ov[1], ov[2], ov[3]);
  ((ushort4*)xr)[o4] = make_ushort4(orr[0], orr[1], orr[2], orr[3]);
  if (t == TT - 1)
    ((float4*)xn_last)[(size_t)b * (DD / 4) + tid] = make_float4(nc[0], nc[1], nc[2], nc[3]);
}

// ---------------- LN2 + token shift + 2 mixes -> bf16 ----------------
__global__ void ln2mix_kernel(const float* __restrict__ x1, const float* __restrict__ ffnx,
                              const float* __restrict__ g, const float* __restrict__ be,
                              const float* __restrict__ cmk, const float* __restrict__ cmr,
                              u16* __restrict__ xk2, u16* __restrict__ xr2,
                              float* __restrict__ xn2_last) {
  int row = blockIdx.x, tid = threadIdx.x;
  int b = row >> 10, t = row & (TT - 1);
  float4 xc = ((const float4*)(x1 + (size_t)row * DD))[tid];
  float4 xp = (t == 0) ? ((const float4*)(ffnx + (size_t)b * DD))[tid]
                       : ((const float4*)(x1 + (size_t)(row - 1) * DD))[tid];
  float sc = xc.x + xc.y + xc.z + xc.w;
  float qc = xc.x * xc.x + xc.y * xc.y + xc.z * xc.z + xc.w * xc.w;
  float sp = xp.x + xp.y + xp.z + xp.w;
  float qp = xp.x * xp.x + xp.y * xp.y + xp.z * xp.z + xp.w * xp.w;
#pragma unroll
  for (int o = 32; o > 0; o >>= 1) {
    sc += __shfl_xor(sc, o); qc += __shfl_xor(qc, o);
    sp += __shfl_xor(sp, o); qp += __shfl_xor(qp, o);
  }
  __shared__ float red[4][4];
  int lane = tid & 63, wid = tid >> 6;
  if (lane == 0) { red[wid][0] = sc; red[wid][1] = qc; red[wid][2] = sp; red[wid][3] = qp; }
  __syncthreads();
  sc = red[0][0] + red[1][0] + red[2][0] + red[3][0];
  qc = red[0][1] + red[1][1] + red[2][1] + red[3][1];
  sp = red[0][2] + red[1][2] + red[2][2] + red[3][2];
  qp = red[0][3] + red[1][3] + red[2][3] + red[3][3];
  const float inv = 1.0f / (float)DD;
  float muc = sc * inv, varc = qc * inv - muc * muc;
  float rc = rsqrtf(varc + 1e-3f);
  float mup = sp * inv, varp = qp * inv - mup * mup;
  float rp = rsqrtf(varp + 1e-3f);
  float4 gg = ((const float4*)g)[tid];
  float4 bb = ((const float4*)be)[tid];
  float4 k4 = ((const float4*)cmk)[tid];
  float4 r4 = ((const float4*)cmr)[tid];
  float xcv[4] = {xc.x, xc.y, xc.z, xc.w};
  float xpv[4] = {xp.x, xp.y, xp.z, xp.w};
  float gv[4] = {gg.x, gg.y, gg.z, gg.w};
  float bv[4] = {bb.x, bb.y, bb.z, bb.w};
  float kv[4] = {k4.x, k4.y, k4.z, k4.w};
  float rv[4] = {r4.x, r4.y, r4.z, r4.w};
  u16 ok[4], orr[4];
  float nc[4];
#pragma unroll
  for (int i = 0; i < 4; i++) {
    nc[i] = (xcv[i] - muc) * rc * gv[i] + bv[i];
    float np = (t == 0) ? xpv[i] : ((xpv[i] - mup) * rp * gv[i] + bv[i]);
    ok[i] = f2bf(nc[i] * kv[i] + np * (1.0f - kv[i]));
    orr[i] = f2bf(nc[i] * rv[i] + np * (1.0f - rv[i]));
  }
  size_t o4 = (size_t)row * (DD / 4) + tid;
  ((ushort4*)xk2)[o4] = make_ushort4(ok[0], ok[1], ok[2], ok[3]);
  ((ushort4*)xr2)[o4] = make_ushort4(orr[0], orr[1], orr[2], orr[3]);
  if (t == TT - 1)
    ((float4*)xn2_last)[(size_t)b * (DD / 4) + tid] = make_float4(nc[0], nc[1], nc[2], nc[3]);
}

// ================= chunked WKV scan =================
// True-value recurrence A' = e^w A + e^k v is linear; chunk of L tokens:
// A_out = e^{Lw} A_in + S_a.  State kept log-normalized as (aa,bb,pp).

// Phase 1: per-(channel,chunk) zero-state chunk sums (sa,sb,ps).
__global__ void wkv_chunk_sum(const float* __restrict__ K, const float* __restrict__ V,
                              const float* __restrict__ decay,
                              float* __restrict__ sa, float* __restrict__ sb,
                              float* __restrict__ ps) {
  int f = blockIdx.x * 256 + threadIdx.x;           // 0 .. NCHAN*NCH-1
  int d = f & (DD - 1);
  int bc = f >> 10;
  int b = bc & (BB - 1);
  int chunk = bc >> 3;
  float w = -__expf(decay[d]);
  const float* kp = K + ((size_t)(b * TT + chunk * CHL)) * DD + d;
  const float* vp = V + ((size_t)(b * TT + chunk * CHL)) * DD + d;
  float aa = 0.0f, bb = 0.0f, pp = -1e30f;
#pragma unroll
  for (int j = 0; j < CHL; j++) {
    float kt = kp[(size_t)j * DD];
    float vt = vp[(size_t)j * DD];
    float ww2 = pp + w;
    float p2 = fmaxf(ww2, kt);
    float e1 = __expf(ww2 - p2);
    float e2 = __expf(kt - p2);
    aa = e1 * aa + e2 * vt;
    bb = e1 * bb + e2;
    pp = p2;
  }
  int ch = b * DD + d;
  size_t s = (size_t)chunk * NCHAN + ch;
  sa[s] = aa; sb[s] = bb; ps[s] = pp;
}

// Phase 2: per-channel scan over chunk summaries -> prefix states + final state.
__global__ void wkv_chunk_scan(const float* __restrict__ sa, const float* __restrict__ sb,
                               const float* __restrict__ ps, const float* __restrict__ decay,
                               const float* __restrict__ aa0, const float* __restrict__ bb0,
                               const float* __restrict__ pp0,
                               float* __restrict__ pa, float* __restrict__ pb,
                               float* __restrict__ ppx,
                               float* __restrict__ aa_out, float* __restrict__ bb_out,
                               float* __restrict__ pp_out) {
  int ch = blockIdx.x * 256 + threadIdx.x;  // 0..NCHAN-1
  int d = ch & (DD - 1);
  float w = -__expf(decay[d]);
  float wL = (float)CHL * w;
  float aa = aa0[ch], bb = bb0[ch], pp = pp0[ch];
  float lsa[NCH], lsb[NCH], lps[NCH];
#pragma unroll
  for (int j = 0; j < NCH; j++) {
    size_t s = (size_t)j * NCHAN + ch;
    lsa[j] = sa[s]; lsb[j] = sb[s]; lps[j] = ps[s];
  }
#pragma unroll
  for (int j = 0; j < NCH; j++) {
    size_t s = (size_t)j * NCHAN + ch;
    pa[s] = aa; pb[s] = bb; ppx[s] = pp;
    float pw = pp + wL;
    float pn = fmaxf(pw, lps[j]);
    float e1 = __expf(pw - pn);
    float e2 = __expf(lps[j] - pn);
    aa = e1 * aa + e2 * lsa[j];
    bb = e1 * bb + e2 * lsb[j];
    pp = pn;
  }
  aa_out[ch] = aa; bb_out[ch] = bb; pp_out[ch] = pp;
}

// Phase 3: per-(channel,chunk) replay from prefix state, emit rm = bf16(sigr * wkv).
__global__ void wkv_chunk_out(const float* __restrict__ K, const float* __restrict__ V,
                              const u16* __restrict__ sigr, const float* __restrict__ decay,
                              const float* __restrict__ first,
                              const float* __restrict__ pa, const float* __restrict__ pb,
                              const float* __restrict__ ppx, u16* __restrict__ rm) {
  int f = blockIdx.x * 256 + threadIdx.x;
  int d = f & (DD - 1);
  int bc = f >> 10;
  int b = bc & (BB - 1);
  int chunk = bc >> 3;
  float w = -__expf(decay[d]);
  float u = first[d];
  int ch = b * DD + d;
  size_t s = (size_t)chunk * NCHAN + ch;
  float aa = pa[s], bb = pb[s], pp = ppx[s];
  size_t base = ((size_t)(b * TT + chunk * CHL)) * DD + d;
  const float* kp = K + base;
  const float* vp = V + base;
  const u16* rp = sigr + base;
  u16* op = rm + base;
#pragma unroll
  for (int j = 0; j < CHL; j++) {
    float kt = kp[(size_t)j * DD];
    float vt = vp[(size_t)j * DD];
    float ww = u + kt;
    float p = fmaxf(pp, ww);
    float e1 = __expf(pp - p);
    float e2 = __expf(ww - p);
    float wkv = __fdividef(e1 * aa + e2 * vt, e1 * bb + e2);
    op[(size_t)j * DD] = f2bf(bf2f(rp[(size_t)j * DD]) * wkv);
    float ww2 = pp + w;
    float p2 = fmaxf(ww2, kt);
    float e1b = __expf(ww2 - p2);
    float e2b = __expf(kt - p2);
    aa = e1b * aa + e2b * vt;
    bb = e1b * bb + e2b;
    pp = p2;
  }
}

// ---------------- bf16 MFMA GEMM, C = A[M,K] @ B (BT given as [N,K]) ----------------
// global_load_lds (width 16) staging; chunk swizzle p=(c+(r>>1))&3 applied on the
// GLOBAL address side (free) so ds_read_b128 fragment reads are 2-way (free) not 8-way.
// MODE 0: C fp32 = A@B
// MODE 1: C bf16 = sigmoid(A@B)
// MODE 2: C bf16 = relu(A@B)^2
// MODE 3: C fp32 = A@B + R1
// MODE 4: C fp32 = R1 + bf2f(R2) * (A@B)

template <int MODE>
__global__ void gemm_bt(const u16* __restrict__ A, const u16* __restrict__ BT,
                        const float* R1, const u16* R2, void* Cout, int M, int N, int K) {
  __shared__ u16 lA[128 * 32];
  __shared__ u16 lB[128 * 32];
  int tid = threadIdx.x;
  int lane = tid & 63;
  int wid = tid >> 6;
  int wy = wid >> 1, wx = wid & 1;
  int m0 = blockIdx.y * 128, n0 = blockIdx.x * 128;
  int rlo = lane & 15;
  // physical u16 offset of this lane's logical k-chunk within an LDS row
  int pread = (((lane >> 4) + (rlo >> 1)) & 3) * 8;

  // staging: lds 16B-chunk i lands at bytes i*16 (wave-uniform base + lane*16).
  // chunk i = row (i>>2), physical chunk (i&3); logical k-chunk c = (p - (r>>1)) & 3.
  int r1 = tid >> 2, c1 = ((tid & 3) - (r1 >> 1)) & 3;
  int r2 = (256 + tid) >> 2, c2 = (((256 + tid) & 3) - (r2 >> 1)) & 3;
  const u16* gA1 = A + (size_t)(m0 + r1) * K + c1 * 8;
  const u16* gA2 = A + (size_t)(m0 + r2) * K + c2 * 8;
  const u16* gB1 = BT + (size_t)(n0 + r1) * K + c1 * 8;
  const u16* gB2 = BT + (size_t)(n0 + r2) * K + c2 * 8;
  u16* ldsA1 = lA + wid * 512;          // bytes wid*1024
  u16* ldsA2 = lA + 2048 + wid * 512;   // bytes 4096 + wid*1024
  u16* ldsB1 = lB + wid * 512;
  u16* ldsB2 = lB + 2048 + wid * 512;

  floatx4 acc[4][4];
#pragma unroll
  for (int mi = 0; mi < 4; mi++)
#pragma unroll
    for (int ni = 0; ni < 4; ni++)
#pragma unroll
      for (int e = 0; e < 4; e++) acc[mi][ni][e] = 0.0f;

  for (int kt = 0; kt < K; kt += 32) {
    __syncthreads();
    __builtin_amdgcn_global_load_lds(gA1 + kt, ldsA1, 16, 0, 0);
    __builtin_amdgcn_global_load_lds(gA2 + kt, ldsA2, 16, 0, 0);
    __builtin_amdgcn_global_load_lds(gB1 + kt, ldsB1, 16, 0, 0);
    __builtin_amdgcn_global_load_lds(gB2 + kt, ldsB2, 16, 0, 0);
    __syncthreads();
    short8 af[4], bfr[4];
#pragma unroll
    for (int mi = 0; mi < 4; mi++)
      af[mi] = *(const short8*)&lA[(wy * 64 + mi * 16 + rlo) * 32 + pread];
#pragma unroll
    for (int ni = 0; ni < 4; ni++)
      bfr[ni] = *(const short8*)&lB[(wx * 64 + ni * 16 + rlo) * 32 + pread];
#pragma unroll
    for (int mi = 0; mi < 4; mi++)
#pragma unroll
      for (int ni = 0; ni < 4; ni++)
        acc[mi][ni] = __builtin_amdgcn_mfma_f32_16x16x32_bf16(af[mi], bfr[ni], acc[mi][ni], 0, 0, 0);
  }

  int rbase = (lane >> 4) * 4;
#pragma unroll
  for (int mi = 0; mi < 4; mi++) {
#pragma unroll
    for (int ni = 0; ni < 4; ni++) {
#pragma unroll
      for (int r = 0; r < 4; r++) {
        int row = m0 + wy * 64 + mi * 16 + rbase + r;
        int col = n0 + wx * 64 + ni * 16 + rlo;
        size_t idx = (size_t)row * N + col;
        float v = acc[mi][ni][r];
        if (MODE == 0) {
          ((float*)Cout)[idx] = v;
        } else if (MODE == 1) {
          ((u16*)Cout)[idx] = f2bf(sigmoidf_(v));
        } else if (MODE == 2) {
          float tpos = fmaxf(v, 0.0f);
          ((u16*)Cout)[idx] = f2bf(tpos * tpos);
        } else if (MODE == 3) {
          ((float*)Cout)[idx] = v + R1[idx];
        } else {
          ((float*)Cout)[idx] = R1[idx] + bf2f(R2[idx]) * v;
        }
      }
    }
  }
}

extern "C" void kernel_launch(void* const* d_in, const int* in_sizes, int n_in,
                              void* d_out, int out_size, void* d_ws, size_t ws_size,
                              hipStream_t stream) {
  const float* x    = (const float*)d_in[0];
  const float* attx = (const float*)d_in[1];
  const float* aa0  = (const float*)d_in[2];
  const float* bb0  = (const float*)d_in[3];
  const float* pp0  = (const float*)d_in[4];
  const float* ffnx = (const float*)d_in[5];
  const float* ln1g = (const float*)d_in[6];
  const float* ln1b = (const float*)d_in[7];
  const float* ln2g = (const float*)d_in[8];
  const float* ln2b = (const float*)d_in[9];
  const float* mk   = (const float*)d_in[10];
  const float* mv   = (const float*)d_in[11];
  const float* mr   = (const float*)d_in[12];
  const float* decay= (const float*)d_in[13];
  const float* first= (const float*)d_in[14];
  const float* Wk   = (const float*)d_in[15];
  const float* Wv   = (const float*)d_in[16];
  const float* Wr   = (const float*)d_in[17];
  const float* Wo   = (const float*)d_in[18];
  const float* cmk  = (const float*)d_in[19];
  const float* cmr  = (const float*)d_in[20];
  const float* Ck   = (const float*)d_in[21];
  const float* Cr   = (const float*)d_in[22];
  const float* Cv   = (const float*)d_in[23];

  float* out      = (float*)d_out;
  float* xn_last  = out + (size_t)BB * TT * DD;
  float* aa_out   = xn_last + BB * DD;
  float* bb_out   = aa_out + BB * DD;
  float* pp_out   = bb_out + BB * DD;
  float* xn2_last = pp_out + BB * DD;
  float* x1 = out;  // x1 lives in the out buffer (final epilogue reads R1[idx] then writes same idx)

  char* ws = (char*)d_ws;
  const size_t MB = 1024ull * 1024ull;
  u16* WkT   = (u16*)(ws + 0 * MB);     // 2MB each
  u16* WvT   = (u16*)(ws + 2 * MB);
  u16* WrT   = (u16*)(ws + 4 * MB);
  u16* WoT   = (u16*)(ws + 6 * MB);
  u16* CrT   = (u16*)(ws + 8 * MB);
  u16* CkT   = (u16*)(ws + 10 * MB);    // 8MB  [4096,1024]
  u16* CvT   = (u16*)(ws + 18 * MB);    // 8MB  [1024,4096]
  u16* xk    = (u16*)(ws + 26 * MB);    // 16MB
  u16* xv    = (u16*)(ws + 42 * MB);    // 16MB
  u16* xr    = (u16*)(ws + 58 * MB);    // 16MB
  float* kbuf= (float*)(ws + 74 * MB);  // 32MB
  float* vbuf= (float*)(ws + 106 * MB); // 32MB
  u16* sigr  = (u16*)(ws + 138 * MB);   // 16MB
  float* sab = (float*)(ws + 154 * MB); // 1MB each: sa,sb,ps,pa,pb,ppx -> peak 160MB
  float* sbb = (float*)(ws + 155 * MB);
  float* psb = (float*)(ws + 156 * MB);
  float* pab = (float*)(ws + 157 * MB);
  float* pbb = (float*)(ws + 158 * MB);
  float* ppb = (float*)(ws + 159 * MB);
  // reuse (lifetimes disjoint):
  u16* rmb   = (u16*)(ws + 26 * MB);    // over xk (dead after Wk GEMM)
  u16* xk2   = (u16*)(ws + 26 * MB);    // over rmb (dead after Wo GEMM)
  u16* xr2   = (u16*)(ws + 42 * MB);    // over xv
  u16* sigr2 = (u16*)(ws + 58 * MB);    // over xr
  u16* kc    = (u16*)(ws + 74 * MB);    // 64MB over kbuf+vbuf (dead after wkv phase3)

  dim3 tb32(32, 8);
  transpose_bf16<<<dim3(32, 32), tb32, 0, stream>>>(Wk, WkT, 1024, 1024);
  transpose_bf16<<<dim3(32, 32), tb32, 0, stream>>>(Wv, WvT, 1024, 1024);
  transpose_bf16<<<dim3(32, 32), tb32, 0, stream>>>(Wr, WrT, 1024, 1024);
  transpose_bf16<<<dim3(32, 32), tb32, 0, stream>>>(Wo, WoT, 1024, 1024);
  transpose_bf16<<<dim3(32, 32), tb32, 0, stream>>>(Cr, CrT, 1024, 1024);
  transpose_bf16<<<dim3(128, 32), tb32, 0, stream>>>(Ck, CkT, 1024, 4096);
  transpose_bf16<<<dim3(32, 128), tb32, 0, stream>>>(Cv, CvT, 4096, 1024);

  ln1mix_kernel<<<MM, 256, 0, stream>>>(x, attx, ln1g, ln1b, mk, mv, mr, xk, xv, xr, xn_last);

  gemm_bt<0><<<dim3(8, 64), 256, 0, stream>>>(xk, WkT, nullptr, nullptr, kbuf, MM, 1024, 1024);
  gemm_bt<0><<<dim3(8, 64), 256, 0, stream>>>(xv, WvT, nullptr, nullptr, vbuf, MM, 1024, 1024);
  gemm_bt<1><<<dim3(8, 64), 256, 0, stream>>>(xr, WrT, nullptr, nullptr, sigr, MM, 1024, 1024);

  wkv_chunk_sum<<<NCHAN * NCH / 256, 256, 0, stream>>>(kbuf, vbuf, decay, sab, sbb, psb);
  wkv_chunk_scan<<<NCHAN / 256, 256, 0, stream>>>(sab, sbb, psb, decay, aa0, bb0, pp0,
                                                  pab, pbb, ppb, aa_out, bb_out, pp_out);
  wkv_chunk_out<<<NCHAN * NCH / 256, 256, 0, stream>>>(kbuf, vbuf, sigr, decay, first,
                                                       pab, pbb, ppb, rmb);

  gemm_bt<3><<<dim3(8, 64), 256, 0, stream>>>(rmb, WoT, x, nullptr, x1, MM, 1024, 1024);

  ln2mix_kernel<<<MM, 256, 0, stream>>>(x1, ffnx, ln2g, ln2b, cmk, cmr, xk2, xr2, xn2_last);

  gemm_bt<2><<<dim3(32, 64), 256, 0, stream>>>(xk2, CkT, nullptr, nullptr, kc, MM, 4096, 1024);
  gemm_bt<1><<<dim3(8, 64), 256, 0, stream>>>(xr2, CrT, nullptr, nullptr, sigr2, MM, 1024, 1024);
  gemm_bt<4><<<dim3(8, 64), 256, 0, stream>>>(kc, CvT, x1, sigr2, out, MM, 1024, 4096);
}

// Round 3
// 511.780 us; speedup vs baseline: 1.4757x; 1.1262x over previous
//
#include <hip/hip_runtime.h>

#define TT 1024
#define DD 1024
#define BB 8
#define FF 4096
#define MM (BB * TT)
#define CHL 32                 // WKV chunk length
#define NCH (TT / CHL)         // 32 chunks
#define NCHAN (BB * DD)        // 8192 channels

typedef unsigned short u16;
typedef unsigned int u32;

typedef __attribute__((ext_vector_type(8))) short short8;
typedef __attribute__((ext_vector_type(4))) float floatx4;

__device__ __forceinline__ u16 f2bf(float f) {
  u32 u = __float_as_uint(f);
  u32 r = (u + 0x7fffu + ((u >> 16) & 1u)) >> 16;
  return (u16)r;
}
__device__ __forceinline__ float bf2f(u16 h) { return __uint_as_float(((u32)h) << 16); }
__device__ __forceinline__ float sigmoidf_(float v) { return 1.0f / (1.0f + __expf(-v)); }

// ---------------- weight transposes fp32[K,N] -> bf16[N,K] ----------------
// batched over the five 1024x1024 weights via blockIdx.z
__global__ void transpose5_bf16(const float* __restrict__ w0, const float* __restrict__ w1,
                                const float* __restrict__ w2, const float* __restrict__ w3,
                                const float* __restrict__ w4, u16* __restrict__ outbase) {
  __shared__ float tile[32][33];
  const float* srcs[5] = {w0, w1, w2, w3, w4};
  const float* in = srcs[blockIdx.z];
  u16* out = outbase + (size_t)blockIdx.z * 1024 * 1024;
  int tx = threadIdx.x, ty = threadIdx.y;
  int n0 = blockIdx.x * 32, k0 = blockIdx.y * 32;
#pragma unroll
  for (int j = 0; j < 32; j += 8)
    tile[ty + j][tx] = in[(size_t)(k0 + ty + j) * 1024 + (n0 + tx)];
  __syncthreads();
#pragma unroll
  for (int j = 0; j < 32; j += 8)
    out[(size_t)(n0 + ty + j) * 1024 + (k0 + tx)] = f2bf(tile[tx][ty + j]);
}

__global__ void transpose_bf16(const float* __restrict__ in, u16* __restrict__ out, int K, int N) {
  __shared__ float tile[32][33];
  int tx = threadIdx.x, ty = threadIdx.y;
  int n0 = blockIdx.x * 32, k0 = blockIdx.y * 32;
#pragma unroll
  for (int j = 0; j < 32; j += 8)
    tile[ty + j][tx] = in[(size_t)(k0 + ty + j) * N + (n0 + tx)];
  __syncthreads();
#pragma unroll
  for (int j = 0; j < 32; j += 8)
    out[(size_t)(n0 + ty + j) * K + (k0 + tx)] = f2bf(tile[tx][ty + j]);
}

// ---------------- LN1 + token shift + 3 mixes -> bf16 ----------------
__global__ void ln1mix_kernel(const float* __restrict__ x, const float* __restrict__ attx,
                              const float* __restrict__ g, const float* __restrict__ be,
                              const float* __restrict__ mk, const float* __restrict__ mv,
                              const float* __restrict__ mr,
                              u16* __restrict__ xk, u16* __restrict__ xv, u16* __restrict__ xr,
                              float* __restrict__ xn_last) {
  int row = blockIdx.x, tid = threadIdx.x;
  int b = row >> 10, t = row & (TT - 1);
  float4 xc = ((const float4*)(x + (size_t)row * DD))[tid];
  float4 xp = (t == 0) ? ((const float4*)(attx + (size_t)b * DD))[tid]
                       : ((const float4*)(x + (size_t)(row - 1) * DD))[tid];
  float sc = xc.x + xc.y + xc.z + xc.w;
  float qc = xc.x * xc.x + xc.y * xc.y + xc.z * xc.z + xc.w * xc.w;
  float sp = xp.x + xp.y + xp.z + xp.w;
  float qp = xp.x * xp.x + xp.y * xp.y + xp.z * xp.z + xp.w * xp.w;
#pragma unroll
  for (int o = 32; o > 0; o >>= 1) {
    sc += __shfl_xor(sc, o); qc += __shfl_xor(qc, o);
    sp += __shfl_xor(sp, o); qp += __shfl_xor(qp, o);
  }
  __shared__ float red[4][4];
  int lane = tid & 63, wid = tid >> 6;
  if (lane == 0) { red[wid][0] = sc; red[wid][1] = qc; red[wid][2] = sp; red[wid][3] = qp; }
  __syncthreads();
  sc = red[0][0] + red[1][0] + red[2][0] + red[3][0];
  qc = red[0][1] + red[1][1] + red[2][1] + red[3][1];
  sp = red[0][2] + red[1][2] + red[2][2] + red[3][2];
  qp = red[0][3] + red[1][3] + red[2][3] + red[3][3];
  const float inv = 1.0f / (float)DD;
  float muc = sc * inv, varc = qc * inv - muc * muc;
  float rc = rsqrtf(varc + 1e-3f);
  float mup = sp * inv, varp = qp * inv - mup * mup;
  float rp = rsqrtf(varp + 1e-3f);
  float4 gg = ((const float4*)g)[tid];
  float4 bb = ((const float4*)be)[tid];
  float4 k4 = ((const float4*)mk)[tid];
  float4 v4 = ((const float4*)mv)[tid];
  float4 r4 = ((const float4*)mr)[tid];
  float xcv[4] = {xc.x, xc.y, xc.z, xc.w};
  float xpv[4] = {xp.x, xp.y, xp.z, xp.w};
  float gv[4] = {gg.x, gg.y, gg.z, gg.w};
  float bv[4] = {bb.x, bb.y, bb.z, bb.w};
  float kv[4] = {k4.x, k4.y, k4.z, k4.w};
  float vv[4] = {v4.x, v4.y, v4.z, v4.w};
  float rv[4] = {r4.x, r4.y, r4.z, r4.w};
  u16 ok[4], ov[4], orr[4];
  float nc[4];
#pragma unroll
  for (int i = 0; i < 4; i++) {
    nc[i] = (xcv[i] - muc) * rc * gv[i] + bv[i];
    float np = (t == 0) ? xpv[i] : ((xpv[i] - mup) * rp * gv[i] + bv[i]);
    ok[i] = f2bf(nc[i] * kv[i] + np * (1.0f - kv[i]));
    ov[i] = f2bf(nc[i] * vv[i] + np * (1.0f - vv[i]));
    orr[i] = f2bf(nc[i] * rv[i] + np * (1.0f - rv[i]));
  }
  size_t o4 = (size_t)row * (DD / 4) + tid;
  ((ushort4*)xk)[o4] = make_ushort4(ok[0], ok[1], ok[2], ok[3]);
  ((ushort4*)xv)[o4] = make_ushort4(ov[0], ov[1], ov[2], ov[3]);
  ((ushort4*)xr)[o4] = make_ushort4(orr[0], orr[1], orr[2], orr[3]);
  if (t == TT - 1)
    ((float4*)xn_last)[(size_t)b * (DD / 4) + tid] = make_float4(nc[0], nc[1], nc[2], nc[3]);
}

// ---------------- LN2 + token shift + 2 mixes -> bf16 ----------------
__global__ void ln2mix_kernel(const float* __restrict__ x1, const float* __restrict__ ffnx,
                              const float* __restrict__ g, const float* __restrict__ be,
                              const float* __restrict__ cmk, const float* __restrict__ cmr,
                              u16* __restrict__ xk2, u16* __restrict__ xr2,
                              float* __restrict__ xn2_last) {
  int row = blockIdx.x, tid = threadIdx.x;
  int b = row >> 10, t = row & (TT - 1);
  float4 xc = ((const float4*)(x1 + (size_t)row * DD))[tid];
  float4 xp = (t == 0) ? ((const float4*)(ffnx + (size_t)b * DD))[tid]
                       : ((const float4*)(x1 + (size_t)(row - 1) * DD))[tid];
  float sc = xc.x + xc.y + xc.z + xc.w;
  float qc = xc.x * xc.x + xc.y * xc.y + xc.z * xc.z + xc.w * xc.w;
  float sp = xp.x + xp.y + xp.z + xp.w;
  float qp = xp.x * xp.x + xp.y * xp.y + xp.z * xp.z + xp.w * xp.w;
#pragma unroll
  for (int o = 32; o > 0; o >>= 1) {
    sc += __shfl_xor(sc, o); qc += __shfl_xor(qc, o);
    sp += __shfl_xor(sp, o); qp += __shfl_xor(qp, o);
  }
  __shared__ float red[4][4];
  int lane = tid & 63, wid = tid >> 6;
  if (lane == 0) { red[wid][0] = sc; red[wid][1] = qc; red[wid][2] = sp; red[wid][3] = qp; }
  __syncthreads();
  sc = red[0][0] + red[1][0] + red[2][0] + red[3][0];
  qc = red[0][1] + red[1][1] + red[2][1] + red[3][1];
  sp = red[0][2] + red[1][2] + red[2][2] + red[3][2];
  qp = red[0][3] + red[1][3] + red[2][3] + red[3][3];
  const float inv = 1.0f / (float)DD;
  float muc = sc * inv, varc = qc * inv - muc * muc;
  float rc = rsqrtf(varc + 1e-3f);
  float mup = sp * inv, varp = qp * inv - mup * mup;
  float rp = rsqrtf(varp + 1e-3f);
  float4 gg = ((const float4*)g)[tid];
  float4 bb = ((const float4*)be)[tid];
  float4 k4 = ((const float4*)cmk)[tid];
  float4 r4 = ((const float4*)cmr)[tid];
  float xcv[4] = {xc.x, xc.y, xc.z, xc.w};
  float xpv[4] = {xp.x, xp.y, xp.z, xp.w};
  float gv[4] = {gg.x, gg.y, gg.z, gg.w};
  float bv[4] = {bb.x, bb.y, bb.z, bb.w};
  float kv[4] = {k4.x, k4.y, k4.z, k4.w};
  float rv[4] = {r4.x, r4.y, r4.z, r4.w};
  u16 ok[4], orr[4];
  float nc[4];
#pragma unroll
  for (int i = 0; i < 4; i++) {
    nc[i] = (xcv[i] - muc) * rc * gv[i] + bv[i];
    float np = (t == 0) ? xpv[i] : ((xpv[i] - mup) * rp * gv[i] + bv[i]);
    ok[i] = f2bf(nc[i] * kv[i] + np * (1.0f - kv[i]));
    orr[i] = f2bf(nc[i] * rv[i] + np * (1.0f - rv[i]));
  }
  size_t o4 = (size_t)row * (DD / 4) + tid;
  ((ushort4*)xk2)[o4] = make_ushort4(ok[0], ok[1], ok[2], ok[3]);
  ((ushort4*)xr2)[o4] = make_ushort4(orr[0], orr[1], orr[2], orr[3]);
  if (t == TT - 1)
    ((float4*)xn2_last)[(size_t)b * (DD / 4) + tid] = make_float4(nc[0], nc[1], nc[2], nc[3]);
}

// ================= chunked WKV scan =================
__global__ void wkv_chunk_sum(const float* __restrict__ K, const float* __restrict__ V,
                              const float* __restrict__ decay,
                              float* __restrict__ sa, float* __restrict__ sb,
                              float* __restrict__ ps) {
  int f = blockIdx.x * 256 + threadIdx.x;           // 0 .. NCHAN*NCH-1
  int d = f & (DD - 1);
  int bc = f >> 10;
  int b = bc & (BB - 1);
  int chunk = bc >> 3;
  float w = -__expf(decay[d]);
  const float* kp = K + ((size_t)(b * TT + chunk * CHL)) * DD + d;
  const float* vp = V + ((size_t)(b * TT + chunk * CHL)) * DD + d;
  float aa = 0.0f, bb = 0.0f, pp = -1e30f;
#pragma unroll
  for (int j = 0; j < CHL; j++) {
    float kt = kp[(size_t)j * DD];
    float vt = vp[(size_t)j * DD];
    float ww2 = pp + w;
    float p2 = fmaxf(ww2, kt);
    float e1 = __expf(ww2 - p2);
    float e2 = __expf(kt - p2);
    aa = e1 * aa + e2 * vt;
    bb = e1 * bb + e2;
    pp = p2;
  }
  int ch = b * DD + d;
  size_t s = (size_t)chunk * NCHAN + ch;
  sa[s] = aa; sb[s] = bb; ps[s] = pp;
}

__global__ void wkv_chunk_scan(const float* __restrict__ sa, const float* __restrict__ sb,
                               const float* __restrict__ ps, const float* __restrict__ decay,
                               const float* __restrict__ aa0, const float* __restrict__ bb0,
                               const float* __restrict__ pp0,
                               float* __restrict__ pa, float* __restrict__ pb,
                               float* __restrict__ ppx,
                               float* __restrict__ aa_out, float* __restrict__ bb_out,
                               float* __restrict__ pp_out) {
  int ch = blockIdx.x * 256 + threadIdx.x;  // 0..NCHAN-1
  int d = ch & (DD - 1);
  float w = -__expf(decay[d]);
  float wL = (float)CHL * w;
  float aa = aa0[ch], bb = bb0[ch], pp = pp0[ch];
  float lsa[NCH], lsb[NCH], lps[NCH];
#pragma unroll
  for (int j = 0; j < NCH; j++) {
    size_t s = (size_t)j * NCHAN + ch;
    lsa[j] = sa[s]; lsb[j] = sb[s]; lps[j] = ps[s];
  }
#pragma unroll
  for (int j = 0; j < NCH; j++) {
    size_t s = (size_t)j * NCHAN + ch;
    pa[s] = aa; pb[s] = bb; ppx[s] = pp;
    float pw = pp + wL;
    float pn = fmaxf(pw, lps[j]);
    float e1 = __expf(pw - pn);
    float e2 = __expf(lps[j] - pn);
    aa = e1 * aa + e2 * lsa[j];
    bb = e1 * bb + e2 * lsb[j];
    pp = pn;
  }
  aa_out[ch] = aa; bb_out[ch] = bb; pp_out[ch] = pp;
}

__global__ void wkv_chunk_out(const float* __restrict__ K, const float* __restrict__ V,
                              const u16* __restrict__ sigr, const float* __restrict__ decay,
                              const float* __restrict__ first,
                              const float* __restrict__ pa, const float* __restrict__ pb,
                              const float* __restrict__ ppx, u16* __restrict__ rm) {
  int f = blockIdx.x * 256 + threadIdx.x;
  int d = f & (DD - 1);
  int bc = f >> 10;
  int b = bc & (BB - 1);
  int chunk = bc >> 3;
  float w = -__expf(decay[d]);
  float u = first[d];
  int ch = b * DD + d;
  size_t s = (size_t)chunk * NCHAN + ch;
  float aa = pa[s], bb = pb[s], pp = ppx[s];
  size_t base = ((size_t)(b * TT + chunk * CHL)) * DD + d;
  const float* kp = K + base;
  const float* vp = V + base;
  const u16* rp = sigr + base;
  u16* op = rm + base;
#pragma unroll
  for (int j = 0; j < CHL; j++) {
    float kt = kp[(size_t)j * DD];
    float vt = vp[(size_t)j * DD];
    float ww = u + kt;
    float p = fmaxf(pp, ww);
    float e1 = __expf(pp - p);
    float e2 = __expf(ww - p);
    float wkv = __fdividef(e1 * aa + e2 * vt, e1 * bb + e2);
    op[(size_t)j * DD] = f2bf(bf2f(rp[(size_t)j * DD]) * wkv);
    float ww2 = pp + w;
    float p2 = fmaxf(ww2, kt);
    float e1b = __expf(ww2 - p2);
    float e2b = __expf(kt - p2);
    aa = e1b * aa + e2b * vt;
    bb = e1b * bb + e2b;
    pp = p2;
  }
}

// ---------------- bf16 MFMA GEMM, C = A[M,K] @ B (BT given as [N,K]) ----------------
// BK=64, global_load_lds width-16 staging, row-swizzled LDS (pc=(c+r)&7),
// XCD-slab rasterization (flat&7 -> disjoint 8-m-row slab; n outer, m inner).
// MODE 0: C fp32 = A@B
// MODE 1: C bf16 = sigmoid(A@B)
// MODE 2: C bf16 = relu(A@B)^2
// MODE 3: C fp32 = A@B + R1
// MODE 4: C fp32 = R1 + bf2f(R2) * (A@B)
// MODE 5: batched QKV: z=0 fp32->C0, z=1 fp32->C1, z=2 sigmoid bf16->C2

template <int MODE>
__launch_bounds__(256, 3)
__global__ void gemm_bt(const u16* __restrict__ A0, const u16* __restrict__ BT0,
                        const float* R1, const u16* R2,
                        void* C0, void* C1, void* C2, int M, int N, int K) {
  __shared__ u16 lA[128 * 64];
  __shared__ u16 lB[128 * 64];
  int tid = threadIdx.x;
  int lane = tid & 63;
  int wid = tid >> 6;
  int wy = wid >> 1, wx = wid & 1;

  const u16* A = A0;
  const u16* BT = BT0;
  void* Cout = C0;
  if (MODE == 5) {
    int z = blockIdx.z;
    A = A0 + (size_t)z * M * K;
    BT = BT0 + (size_t)z * N * K;
    Cout = (z == 0) ? C0 : (z == 1) ? C1 : C2;
  }

  // XCD-slab raster: flat&7 = m-slab (requires gridDim.y==64)
  int bx = blockIdx.x, by = blockIdx.y;
  {
    int flat = by * gridDim.x + bx;
    int j = flat >> 3;
    by = (flat & 7) * 8 + (j & 7);
    bx = j >> 3;
  }
  int m0 = by * 128, n0 = bx * 128;

  int rlo = lane & 15;
  // staging addressing: chunk i = q*256+tid; r=i>>3, pc=i&7, c=(pc-r)&7 (q-indep)
  int rr = tid >> 3;
  int cc = ((tid & 7) - rr) & 7;
  const u16* gA = A + (size_t)(m0 + rr) * K + cc * 8;
  const u16* gB = BT + (size_t)(n0 + rr) * K + cc * 8;
  u16* ldsA = lA + wid * 512;
  u16* ldsB = lB + wid * 512;
  size_t qstep = (size_t)32 * K;

  floatx4 acc[4][4];
#pragma unroll
  for (int mi = 0; mi < 4; mi++)
#pragma unroll
    for (int ni = 0; ni < 4; ni++)
#pragma unroll
      for (int e = 0; e < 4; e++) acc[mi][ni][e] = 0.0f;

  for (int kt = 0; kt < K; kt += 64) {
    __syncthreads();
#pragma unroll
    for (int q = 0; q < 4; q++) {
      __builtin_amdgcn_global_load_lds(gA + q * qstep + kt, ldsA + q * 2048, 16, 0, 0);
      __builtin_amdgcn_global_load_lds(gB + q * qstep + kt, ldsB + q * 2048, 16, 0, 0);
    }
    __syncthreads();
    short8 af[2][4], bfr[2][4];
#pragma unroll
    for (int s = 0; s < 2; s++) {
      int cbase = s * 4 + (lane >> 4);
#pragma unroll
      for (int mi = 0; mi < 4; mi++) {
        int row = wy * 64 + mi * 16 + rlo;
        af[s][mi] = *(const short8*)&lA[row * 64 + (((cbase + row) & 7) << 3)];
      }
#pragma unroll
      for (int ni = 0; ni < 4; ni++) {
        int row = wx * 64 + ni * 16 + rlo;
        bfr[s][ni] = *(const short8*)&lB[row * 64 + (((cbase + row) & 7) << 3)];
      }
    }
#pragma unroll
    for (int s = 0; s < 2; s++)
#pragma unroll
      for (int mi = 0; mi < 4; mi++)
#pragma unroll
        for (int ni = 0; ni < 4; ni++)
          acc[mi][ni] =
              __builtin_amdgcn_mfma_f32_16x16x32_bf16(af[s][mi], bfr[s][ni], acc[mi][ni], 0, 0, 0);
  }

  int rbase = (lane >> 4) * 4;
#pragma unroll
  for (int mi = 0; mi < 4; mi++) {
#pragma unroll
    for (int ni = 0; ni < 4; ni++) {
#pragma unroll
      for (int r = 0; r < 4; r++) {
        int row = m0 + wy * 64 + mi * 16 + rbase + r;
        int col = n0 + wx * 64 + ni * 16 + rlo;
        size_t idx = (size_t)row * N + col;
        float v = acc[mi][ni][r];
        if (MODE == 0) {
          ((float*)Cout)[idx] = v;
        } else if (MODE == 1) {
          ((u16*)Cout)[idx] = f2bf(sigmoidf_(v));
        } else if (MODE == 2) {
          float tpos = fmaxf(v, 0.0f);
          ((u16*)Cout)[idx] = f2bf(tpos * tpos);
        } else if (MODE == 3) {
          ((float*)Cout)[idx] = v + R1[idx];
        } else if (MODE == 4) {
          ((float*)Cout)[idx] = R1[idx] + bf2f(R2[idx]) * v;
        } else {  // MODE 5
          if (blockIdx.z == 2)
            ((u16*)Cout)[idx] = f2bf(sigmoidf_(v));
          else
            ((float*)Cout)[idx] = v;
        }
      }
    }
  }
}

extern "C" void kernel_launch(void* const* d_in, const int* in_sizes, int n_in,
                              void* d_out, int out_size, void* d_ws, size_t ws_size,
                              hipStream_t stream) {
  const float* x    = (const float*)d_in[0];
  const float* attx = (const float*)d_in[1];
  const float* aa0  = (const float*)d_in[2];
  const float* bb0  = (const float*)d_in[3];
  const float* pp0  = (const float*)d_in[4];
  const float* ffnx = (const float*)d_in[5];
  const float* ln1g = (const float*)d_in[6];
  const float* ln1b = (const float*)d_in[7];
  const float* ln2g = (const float*)d_in[8];
  const float* ln2b = (const float*)d_in[9];
  const float* mk   = (const float*)d_in[10];
  const float* mv   = (const float*)d_in[11];
  const float* mr   = (const float*)d_in[12];
  const float* decay= (const float*)d_in[13];
  const float* first= (const float*)d_in[14];
  const float* Wk   = (const float*)d_in[15];
  const float* Wv   = (const float*)d_in[16];
  const float* Wr   = (const float*)d_in[17];
  const float* Wo   = (const float*)d_in[18];
  const float* cmk  = (const float*)d_in[19];
  const float* cmr  = (const float*)d_in[20];
  const float* Ck   = (const float*)d_in[21];
  const float* Cr   = (const float*)d_in[22];
  const float* Cv   = (const float*)d_in[23];

  float* out      = (float*)d_out;
  float* xn_last  = out + (size_t)BB * TT * DD;
  float* aa_out   = xn_last + BB * DD;
  float* bb_out   = aa_out + BB * DD;
  float* pp_out   = bb_out + BB * DD;
  float* xn2_last = pp_out + BB * DD;
  float* x1 = out;  // x1 lives in the out buffer

  char* ws = (char*)d_ws;
  const size_t MB = 1024ull * 1024ull;
  u16* WT5   = (u16*)(ws + 0 * MB);     // Wk,Wv,Wr,Wo,Cr transposed bf16, 2MB each
  u16* WkT   = WT5;
  u16* WoT   = (u16*)(ws + 6 * MB);
  u16* CrT   = (u16*)(ws + 8 * MB);
  u16* CkT   = (u16*)(ws + 10 * MB);    // 8MB  [4096,1024]
  u16* CvT   = (u16*)(ws + 18 * MB);    // 8MB  [1024,4096]
  u16* xk    = (u16*)(ws + 26 * MB);    // 16MB (xk,xv,xr contiguous for batched QKV)
  u16* xv    = (u16*)(ws + 42 * MB);
  u16* xr    = (u16*)(ws + 58 * MB);
  float* kbuf= (float*)(ws + 74 * MB);  // 32MB
  float* vbuf= (float*)(ws + 106 * MB); // 32MB
  u16* sigr  = (u16*)(ws + 138 * MB);   // 16MB
  float* sab = (float*)(ws + 154 * MB); // 1MB each
  float* sbb = (float*)(ws + 155 * MB);
  float* psb = (float*)(ws + 156 * MB);
  float* pab = (float*)(ws + 157 * MB);
  float* pbb = (float*)(ws + 158 * MB);
  float* ppb = (float*)(ws + 159 * MB);
  // reuse (lifetimes disjoint):
  u16* rmb   = (u16*)(ws + 26 * MB);
  u16* xk2   = (u16*)(ws + 26 * MB);
  u16* xr2   = (u16*)(ws + 42 * MB);
  u16* sigr2 = (u16*)(ws + 58 * MB);
  u16* kc    = (u16*)(ws + 74 * MB);    // 64MB over kbuf+vbuf

  dim3 tb32(32, 8);
  transpose5_bf16<<<dim3(32, 32, 5), tb32, 0, stream>>>(Wk, Wv, Wr, Wo, Cr, WT5);
  transpose_bf16<<<dim3(128, 32), tb32, 0, stream>>>(Ck, CkT, 1024, 4096);
  transpose_bf16<<<dim3(32, 128), tb32, 0, stream>>>(Cv, CvT, 4096, 1024);

  ln1mix_kernel<<<MM, 256, 0, stream>>>(x, attx, ln1g, ln1b, mk, mv, mr, xk, xv, xr, xn_last);

  // batched QKV: z=0 -> kbuf (fp32), z=1 -> vbuf (fp32), z=2 -> sigr (sigmoid bf16)
  gemm_bt<5><<<dim3(8, 64, 3), 256, 0, stream>>>(xk, WkT, nullptr, nullptr,
                                                 kbuf, vbuf, sigr, MM, 1024, 1024);

  wkv_chunk_sum<<<NCHAN * NCH / 256, 256, 0, stream>>>(kbuf, vbuf, decay, sab, sbb, psb);
  wkv_chunk_scan<<<NCHAN / 256, 256, 0, stream>>>(sab, sbb, psb, decay, aa0, bb0, pp0,
                                                  pab, pbb, ppb, aa_out, bb_out, pp_out);
  wkv_chunk_out<<<NCHAN * NCH / 256, 256, 0, stream>>>(kbuf, vbuf, sigr, decay, first,
                                                       pab, pbb, ppb, rmb);

  gemm_bt<3><<<dim3(8, 64), 256, 0, stream>>>(rmb, WoT, x, nullptr, x1, nullptr, nullptr,
                                              MM, 1024, 1024);

  ln2mix_kernel<<<MM, 256, 0, stream>>>(x1, ffnx, ln2g, ln2b, cmk, cmr, xk2, xr2, xn2_last);

  gemm_bt<2><<<dim3(32, 64), 256, 0, stream>>>(xk2, CkT, nullptr, nullptr, kc, nullptr, nullptr,
                                               MM, 4096, 1024);
  gemm_bt<1><<<dim3(8, 64), 256, 0, stream>>>(xr2, CrT, nullptr, nullptr, sigr2, nullptr, nullptr,
                                              MM, 1024, 1024);
  gemm_bt<4><<<dim3(8, 64), 256, 0, stream>>>(kc, CvT, x1, sigr2, out, nullptr, nullptr,
                                              MM, 1024, 4096);
}

// Round 5
// 502.803 us; speedup vs baseline: 1.5021x; 1.0179x over previous
//
#include <hip/hip_runtime.h>

#define TT 1024
#define DD 1024
#define BB 8
#define FF 4096
#define MM (BB * TT)
#define CHL 32                 // WKV chunk length
#define NCH (TT / CHL)         // 32 chunks
#define NCHAN (BB * DD)        // 8192 channels

typedef unsigned short u16;
typedef unsigned int u32;

typedef __attribute__((ext_vector_type(8))) short short8;
typedef __attribute__((ext_vector_type(4))) float floatx4;

__device__ __forceinline__ u16 f2bf(float f) {
  u32 u = __float_as_uint(f);
  u32 r = (u + 0x7fffu + ((u >> 16) & 1u)) >> 16;
  return (u16)r;
}
__device__ __forceinline__ float bf2f(u16 h) { return __uint_as_float(((u32)h) << 16); }
__device__ __forceinline__ float sigmoidf_(float v) { return 1.0f / (1.0f + __expf(-v)); }

// ---------------- weight transposes fp32[K,N] -> bf16[N,K] ----------------
// z=0..3 -> out4 + z*1M (Wk,Wv,Wr,Wo); z=4 -> crdst (Cr lands inside CkCrT)
__global__ void transpose5_bf16(const float* __restrict__ w0, const float* __restrict__ w1,
                                const float* __restrict__ w2, const float* __restrict__ w3,
                                const float* __restrict__ w4,
                                u16* __restrict__ out4, u16* __restrict__ crdst) {
  __shared__ float tile[32][33];
  const float* srcs[5] = {w0, w1, w2, w3, w4};
  const float* in = srcs[blockIdx.z];
  u16* out = (blockIdx.z == 4) ? crdst : out4 + (size_t)blockIdx.z * 1024 * 1024;
  int tx = threadIdx.x, ty = threadIdx.y;
  int n0 = blockIdx.x * 32, k0 = blockIdx.y * 32;
#pragma unroll
  for (int j = 0; j < 32; j += 8)
    tile[ty + j][tx] = in[(size_t)(k0 + ty + j) * 1024 + (n0 + tx)];
  __syncthreads();
#pragma unroll
  for (int j = 0; j < 32; j += 8)
    out[(size_t)(n0 + ty + j) * 1024 + (k0 + tx)] = f2bf(tile[tx][ty + j]);
}

__global__ void transpose_bf16(const float* __restrict__ in, u16* __restrict__ out, int K, int N) {
  __shared__ float tile[32][33];
  int tx = threadIdx.x, ty = threadIdx.y;
  int n0 = blockIdx.x * 32, k0 = blockIdx.y * 32;
#pragma unroll
  for (int j = 0; j < 32; j += 8)
    tile[ty + j][tx] = in[(size_t)(k0 + ty + j) * N + (n0 + tx)];
  __syncthreads();
#pragma unroll
  for (int j = 0; j < 32; j += 8)
    out[(size_t)(n0 + ty + j) * K + (k0 + tx)] = f2bf(tile[tx][ty + j]);
}

// ---------------- LN1 + token shift + 3 mixes -> bf16 ----------------
__global__ void ln1mix_kernel(const float* __restrict__ x, const float* __restrict__ attx,
                              const float* __restrict__ g, const float* __restrict__ be,
                              const float* __restrict__ mk, const float* __restrict__ mv,
                              const float* __restrict__ mr,
                              u16* __restrict__ xk, u16* __restrict__ xv, u16* __restrict__ xr,
                              float* __restrict__ xn_last) {
  int row = blockIdx.x, tid = threadIdx.x;
  int b = row >> 10, t = row & (TT - 1);
  float4 xc = ((const float4*)(x + (size_t)row * DD))[tid];
  float4 xp = (t == 0) ? ((const float4*)(attx + (size_t)b * DD))[tid]
                       : ((const float4*)(x + (size_t)(row - 1) * DD))[tid];
  float sc = xc.x + xc.y + xc.z + xc.w;
  float qc = xc.x * xc.x + xc.y * xc.y + xc.z * xc.z + xc.w * xc.w;
  float sp = xp.x + xp.y + xp.z + xp.w;
  float qp = xp.x * xp.x + xp.y * xp.y + xp.z * xp.z + xp.w * xp.w;
#pragma unroll
  for (int o = 32; o > 0; o >>= 1) {
    sc += __shfl_xor(sc, o); qc += __shfl_xor(qc, o);
    sp += __shfl_xor(sp, o); qp += __shfl_xor(qp, o);
  }
  __shared__ float red[4][4];
  int lane = tid & 63, wid = tid >> 6;
  if (lane == 0) { red[wid][0] = sc; red[wid][1] = qc; red[wid][2] = sp; red[wid][3] = qp; }
  __syncthreads();
  sc = red[0][0] + red[1][0] + red[2][0] + red[3][0];
  qc = red[0][1] + red[1][1] + red[2][1] + red[3][1];
  sp = red[0][2] + red[1][2] + red[2][2] + red[3][2];
  qp = red[0][3] + red[1][3] + red[2][3] + red[3][3];
  const float inv = 1.0f / (float)DD;
  float muc = sc * inv, varc = qc * inv - muc * muc;
  float rc = rsqrtf(varc + 1e-3f);
  float mup = sp * inv, varp = qp * inv - mup * mup;
  float rp = rsqrtf(varp + 1e-3f);
  float4 gg = ((const float4*)g)[tid];
  float4 bb = ((const float4*)be)[tid];
  float4 k4 = ((const float4*)mk)[tid];
  float4 v4 = ((const float4*)mv)[tid];
  float4 r4 = ((const float4*)mr)[tid];
  float xcv[4] = {xc.x, xc.y, xc.z, xc.w};
  float xpv[4] = {xp.x, xp.y, xp.z, xp.w};
  float gv[4] = {gg.x, gg.y, gg.z, gg.w};
  float bv[4] = {bb.x, bb.y, bb.z, bb.w};
  float kv[4] = {k4.x, k4.y, k4.z, k4.w};
  float vv[4] = {v4.x, v4.y, v4.z, v4.w};
  float rv[4] = {r4.x, r4.y, r4.z, r4.w};
  u16 ok[4], ov[4], orr[4];
  float nc[4];
#pragma unroll
  for (int i = 0; i < 4; i++) {
    nc[i] = (xcv[i] - muc) * rc * gv[i] + bv[i];
    float np = (t == 0) ? xpv[i] : ((xpv[i] - mup) * rp * gv[i] + bv[i]);
    ok[i] = f2bf(nc[i] * kv[i] + np * (1.0f - kv[i]));
    ov[i] = f2bf(nc[i] * vv[i] + np * (1.0f - vv[i]));
    orr[i] = f2bf(nc[i] * rv[i] + np * (1.0f - rv[i]));
  }
  size_t o4 = (size_t)row * (DD / 4) + tid;
  ((ushort4*)xk)[o4] = make_ushort4(ok[0], ok[1], ok[2], ok[3]);
  ((ushort4*)xv)[o4] = make_ushort4(ov[0], ov[1], ov[2], ov[3]);
  ((ushort4*)xr)[o4] = make_ushort4(orr[0], orr[1], orr[2], orr[3]);
  if (t == TT - 1)
    ((float4*)xn_last)[(size_t)b * (DD / 4) + tid] = make_float4(nc[0], nc[1], nc[2], nc[3]);
}

// ---------------- LN2 + token shift + 2 mixes -> bf16 ----------------
__global__ void ln2mix_kernel(const float* __restrict__ x1, const float* __restrict__ ffnx,
                              const float* __restrict__ g, const float* __restrict__ be,
                              const float* __restrict__ cmk, const float* __restrict__ cmr,
                              u16* __restrict__ xk2, u16* __restrict__ xr2,
                              float* __restrict__ xn2_last) {
  int row = blockIdx.x, tid = threadIdx.x;
  int b = row >> 10, t = row & (TT - 1);
  float4 xc = ((const float4*)(x1 + (size_t)row * DD))[tid];
  float4 xp = (t == 0) ? ((const float4*)(ffnx + (size_t)b * DD))[tid]
                       : ((const float4*)(x1 + (size_t)(row - 1) * DD))[tid];
  float sc = xc.x + xc.y + xc.z + xc.w;
  float qc = xc.x * xc.x + xc.y * xc.y + xc.z * xc.z + xc.w * xc.w;
  float sp = xp.x + xp.y + xp.z + xp.w;
  float qp = xp.x * xp.x + xp.y * xp.y + xp.z * xp.z + xp.w * xp.w;
#pragma unroll
  for (int o = 32; o > 0; o >>= 1) {
    sc += __shfl_xor(sc, o); qc += __shfl_xor(qc, o);
    sp += __shfl_xor(sp, o); qp += __shfl_xor(qp, o);
  }
  __shared__ float red[4][4];
  int lane = tid & 63, wid = tid >> 6;
  if (lane == 0) { red[wid][0] = sc; red[wid][1] = qc; red[wid][2] = sp; red[wid][3] = qp; }
  __syncthreads();
  sc = red[0][0] + red[1][0] + red[2][0] + red[3][0];
  qc = red[0][1] + red[1][1] + red[2][1] + red[3][1];
  sp = red[0][2] + red[1][2] + red[2][2] + red[3][2];
  qp = red[0][3] + red[1][3] + red[2][3] + red[3][3];
  const float inv = 1.0f / (float)DD;
  float muc = sc * inv, varc = qc * inv - muc * muc;
  float rc = rsqrtf(varc + 1e-3f);
  float mup = sp * inv, varp = qp * inv - mup * mup;
  float rp = rsqrtf(varp + 1e-3f);
  float4 gg = ((const float4*)g)[tid];
  float4 bb = ((const float4*)be)[tid];
  float4 k4 = ((const float4*)cmk)[tid];
  float4 r4 = ((const float4*)cmr)[tid];
  float xcv[4] = {xc.x, xc.y, xc.z, xc.w};
  float xpv[4] = {xp.x, xp.y, xp.z, xp.w};
  float gv[4] = {gg.x, gg.y, gg.z, gg.w};
  float bv[4] = {bb.x, bb.y, bb.z, bb.w};
  float kv[4] = {k4.x, k4.y, k4.z, k4.w};
  float rv[4] = {r4.x, r4.y, r4.z, r4.w};
  u16 ok[4], orr[4];
  float nc[4];
#pragma unroll
  for (int i = 0; i < 4; i++) {
    nc[i] = (xcv[i] - muc) * rc * gv[i] + bv[i];
    float np = (t == 0) ? xpv[i] : ((xpv[i] - mup) * rp * gv[i] + bv[i]);
    ok[i] = f2bf(nc[i] * kv[i] + np * (1.0f - kv[i]));
    orr[i] = f2bf(nc[i] * rv[i] + np * (1.0f - rv[i]));
  }
  size_t o4 = (size_t)row * (DD / 4) + tid;
  ((ushort4*)xk2)[o4] = make_ushort4(ok[0], ok[1], ok[2], ok[3]);
  ((ushort4*)xr2)[o4] = make_ushort4(orr[0], orr[1], orr[2], orr[3]);
  if (t == TT - 1)
    ((float4*)xn2_last)[(size_t)b * (DD / 4) + tid] = make_float4(nc[0], nc[1], nc[2], nc[3]);
}

// ================= chunked WKV scan (k/v in bf16) =================
__global__ void wkv_chunk_sum(const u16* __restrict__ K, const u16* __restrict__ V,
                              const float* __restrict__ decay,
                              float* __restrict__ sa, float* __restrict__ sb,
                              float* __restrict__ ps) {
  int f = blockIdx.x * 256 + threadIdx.x;           // 0 .. NCHAN*NCH-1
  int d = f & (DD - 1);
  int bc = f >> 10;
  int b = bc & (BB - 1);
  int chunk = bc >> 3;
  float w = -__expf(decay[d]);
  const u16* kp = K + ((size_t)(b * TT + chunk * CHL)) * DD + d;
  const u16* vp = V + ((size_t)(b * TT + chunk * CHL)) * DD + d;
  float aa = 0.0f, bb = 0.0f, pp = -1e30f;
#pragma unroll
  for (int j = 0; j < CHL; j++) {
    float kt = bf2f(kp[(size_t)j * DD]);
    float vt = bf2f(vp[(size_t)j * DD]);
    float ww2 = pp + w;
    float p2 = fmaxf(ww2, kt);
    float e1 = __expf(ww2 - p2);
    float e2 = __expf(kt - p2);
    aa = e1 * aa + e2 * vt;
    bb = e1 * bb + e2;
    pp = p2;
  }
  int ch = b * DD + d;
  size_t s = (size_t)chunk * NCHAN + ch;
  sa[s] = aa; sb[s] = bb; ps[s] = pp;
}

__global__ void wkv_chunk_scan(const float* __restrict__ sa, const float* __restrict__ sb,
                               const float* __restrict__ ps, const float* __restrict__ decay,
                               const float* __restrict__ aa0, const float* __restrict__ bb0,
                               const float* __restrict__ pp0,
                               float* __restrict__ pa, float* __restrict__ pb,
                               float* __restrict__ ppx,
                               float* __restrict__ aa_out, float* __restrict__ bb_out,
                               float* __restrict__ pp_out) {
  int ch = blockIdx.x * 256 + threadIdx.x;  // 0..NCHAN-1
  int d = ch & (DD - 1);
  float w = -__expf(decay[d]);
  float wL = (float)CHL * w;
  float aa = aa0[ch], bb = bb0[ch], pp = pp0[ch];
  float lsa[NCH], lsb[NCH], lps[NCH];
#pragma unroll
  for (int j = 0; j < NCH; j++) {
    size_t s = (size_t)j * NCHAN + ch;
    lsa[j] = sa[s]; lsb[j] = sb[s]; lps[j] = ps[s];
  }
#pragma unroll
  for (int j = 0; j < NCH; j++) {
    size_t s = (size_t)j * NCHAN + ch;
    pa[s] = aa; pb[s] = bb; ppx[s] = pp;
    float pw = pp + wL;
    float pn = fmaxf(pw, lps[j]);
    float e1 = __expf(pw - pn);
    float e2 = __expf(lps[j] - pn);
    aa = e1 * aa + e2 * lsa[j];
    bb = e1 * bb + e2 * lsb[j];
    pp = pn;
  }
  aa_out[ch] = aa; bb_out[ch] = bb; pp_out[ch] = pp;
}

__global__ void wkv_chunk_out(const u16* __restrict__ K, const u16* __restrict__ V,
                              const u16* __restrict__ sigr, const float* __restrict__ decay,
                              const float* __restrict__ first,
                              const float* __restrict__ pa, const float* __restrict__ pb,
                              const float* __restrict__ ppx, u16* __restrict__ rm) {
  int f = blockIdx.x * 256 + threadIdx.x;
  int d = f & (DD - 1);
  int bc = f >> 10;
  int b = bc & (BB - 1);
  int chunk = bc >> 3;
  float w = -__expf(decay[d]);
  float u = first[d];
  int ch = b * DD + d;
  size_t s = (size_t)chunk * NCHAN + ch;
  float aa = pa[s], bb = pb[s], pp = ppx[s];
  size_t base = ((size_t)(b * TT + chunk * CHL)) * DD + d;
  const u16* kp = K + base;
  const u16* vp = V + base;
  const u16* rp = sigr + base;
  u16* op = rm + base;
#pragma unroll
  for (int j = 0; j < CHL; j++) {
    float kt = bf2f(kp[(size_t)j * DD]);
    float vt = bf2f(vp[(size_t)j * DD]);
    float ww = u + kt;
    float p = fmaxf(pp, ww);
    float e1 = __expf(pp - p);
    float e2 = __expf(ww - p);
    float wkv = __fdividef(e1 * aa + e2 * vt, e1 * bb + e2);
    op[(size_t)j * DD] = f2bf(bf2f(rp[(size_t)j * DD]) * wkv);
    float ww2 = pp + w;
    float p2 = fmaxf(ww2, kt);
    float e1b = __expf(ww2 - p2);
    float e2b = __expf(kt - p2);
    aa = e1b * aa + e2b * vt;
    bb = e1b * bb + e2b;
    pp = p2;
  }
}

// ---------------- bf16 MFMA GEMM, C = A[M,K] @ B (BT given as [N,K]) ----------------
// BK=64, global_load_lds width-16 staging, row-swizzled LDS (pc=(c+r)&7),
// XCD-slab rasterization (flat&7 -> disjoint 8-m-row slab; n outer, m inner).
// MODE 3: C0 fp32 = A0@B + R1
// MODE 4: C0 fp32 = R1 + bf2f(R2) * (A0@B)
// MODE 5: batched QKV via z: A=A0+z*M*K, B=BT0+z*N*K, C=(u16*)C0+z*M*N;
//         z<2 -> bf16(v), z==2 -> sigmoid bf16
// MODE 6: merged FFN: bx<32 -> A0(xk2)@Ck cols, relu^2 bf16 -> C0 (stride 4096);
//         bx>=32 -> A1(xr2)@Cr cols, sigmoid bf16 -> C1 (stride 1024).
//         B rows taken from concatenated CkCrT at n0=bx*128 (4096+(bx-32)*128 == bx*128).

template <int MODE>
__launch_bounds__(256, 4)
__global__ void gemm_bt(const u16* __restrict__ A0, const u16* __restrict__ A1,
                        const u16* __restrict__ BT0,
                        const float* R1, const u16* R2,
                        void* C0, void* C1, int M, int N, int K) {
  __shared__ u16 lA[128 * 64];
  __shared__ u16 lB[128 * 64];
  int tid = threadIdx.x;
  int lane = tid & 63;
  int wid = tid >> 6;
  int wy = wid >> 1, wx = wid & 1;

  const u16* A = A0;
  const u16* BT = BT0;
  void* Cout = C0;
  if (MODE == 5) {
    int z = blockIdx.z;
    A = A0 + (size_t)z * M * K;
    BT = BT0 + (size_t)z * N * K;
    Cout = (void*)((u16*)C0 + (size_t)z * M * N);
  }

  // XCD-slab raster: flat&7 = m-slab (requires gridDim.y==64)
  int bx = blockIdx.x, by = blockIdx.y;
  {
    int flat = by * gridDim.x + bx;
    int j = flat >> 3;
    by = (flat & 7) * 8 + (j & 7);
    bx = j >> 3;
  }
  int m0 = by * 128, n0 = bx * 128;

  bool isCr = false;
  if (MODE == 6) {
    isCr = (bx >= 32);
    A = isCr ? A1 : A0;   // Cr columns need the r-mix activations
  }

  int rlo = lane & 15;
  // staging addressing: chunk i = q*256+tid; r=i>>3, pc=i&7, c=(pc-r)&7 (q-indep)
  int rr = tid >> 3;
  int cc = ((tid & 7) - rr) & 7;
  const u16* gA = A + (size_t)(m0 + rr) * K + cc * 8;
  const u16* gB = BT + (size_t)(n0 + rr) * K + cc * 8;
  u16* ldsA = lA + wid * 512;
  u16* ldsB = lB + wid * 512;
  size_t qstep = (size_t)32 * K;

  floatx4 acc[4][4];
#pragma unroll
  for (int mi = 0; mi < 4; mi++)
#pragma unroll
    for (int ni = 0; ni < 4; ni++)
#pragma unroll
      for (int e = 0; e < 4; e++) acc[mi][ni][e] = 0.0f;

  for (int kt = 0; kt < K; kt += 64) {
    __syncthreads();
#pragma unroll
    for (int q = 0; q < 4; q++) {
      __builtin_amdgcn_global_load_lds(gA + q * qstep + kt, ldsA + q * 2048, 16, 0, 0);
      __builtin_amdgcn_global_load_lds(gB + q * qstep + kt, ldsB + q * 2048, 16, 0, 0);
    }
    __syncthreads();
    short8 af[2][4], bfr[2][4];
#pragma unroll
    for (int s = 0; s < 2; s++) {
      int cbase = s * 4 + (lane >> 4);
#pragma unroll
      for (int mi = 0; mi < 4; mi++) {
        int row = wy * 64 + mi * 16 + rlo;
        af[s][mi] = *(const short8*)&lA[row * 64 + (((cbase + row) & 7) << 3)];
      }
#pragma unroll
      for (int ni = 0; ni < 4; ni++) {
        int row = wx * 64 + ni * 16 + rlo;
        bfr[s][ni] = *(const short8*)&lB[row * 64 + (((cbase + row) & 7) << 3)];
      }
    }
#pragma unroll
    for (int s = 0; s < 2; s++)
#pragma unroll
      for (int mi = 0; mi < 4; mi++)
#pragma unroll
        for (int ni = 0; ni < 4; ni++)
          acc[mi][ni] =
              __builtin_amdgcn_mfma_f32_16x16x32_bf16(af[s][mi], bfr[s][ni], acc[mi][ni], 0, 0, 0);
  }

  int rbase = (lane >> 4) * 4;
#pragma unroll
  for (int mi = 0; mi < 4; mi++) {
#pragma unroll
    for (int ni = 0; ni < 4; ni++) {
#pragma unroll
      for (int r = 0; r < 4; r++) {
        int row = m0 + wy * 64 + mi * 16 + rbase + r;
        int col = n0 + wx * 64 + ni * 16 + rlo;
        float v = acc[mi][ni][r];
        if (MODE == 6) {
          if (!isCr) {
            float tpos = fmaxf(v, 0.0f);
            ((u16*)C0)[(size_t)row * 4096 + col] = f2bf(tpos * tpos);
          } else {
            ((u16*)C1)[(size_t)row * 1024 + (col - 4096)] = f2bf(sigmoidf_(v));
          }
        } else {
          size_t idx = (size_t)row * N + col;
          if (MODE == 3) {
            ((float*)Cout)[idx] = v + R1[idx];
          } else if (MODE == 4) {
            ((float*)Cout)[idx] = R1[idx] + bf2f(R2[idx]) * v;
          } else if (MODE == 5) {
            ((u16*)Cout)[idx] = (blockIdx.z == 2) ? f2bf(sigmoidf_(v)) : f2bf(v);
          }
        }
      }
    }
  }
}

extern "C" void kernel_launch(void* const* d_in, const int* in_sizes, int n_in,
                              void* d_out, int out_size, void* d_ws, size_t ws_size,
                              hipStream_t stream) {
  const float* x    = (const float*)d_in[0];
  const float* attx = (const float*)d_in[1];
  const float* aa0  = (const float*)d_in[2];
  const float* bb0  = (const float*)d_in[3];
  const float* pp0  = (const float*)d_in[4];
  const float* ffnx = (const float*)d_in[5];
  const float* ln1g = (const float*)d_in[6];
  const float* ln1b = (const float*)d_in[7];
  const float* ln2g = (const float*)d_in[8];
  const float* ln2b = (const float*)d_in[9];
  const float* mk   = (const float*)d_in[10];
  const float* mv   = (const float*)d_in[11];
  const float* mr   = (const float*)d_in[12];
  const float* decay= (const float*)d_in[13];
  const float* first= (const float*)d_in[14];
  const float* Wk   = (const float*)d_in[15];
  const float* Wv   = (const float*)d_in[16];
  const float* Wr   = (const float*)d_in[17];
  const float* Wo   = (const float*)d_in[18];
  const float* cmk  = (const float*)d_in[19];
  const float* cmr  = (const float*)d_in[20];
  const float* Ck   = (const float*)d_in[21];
  const float* Cr   = (const float*)d_in[22];
  const float* Cv   = (const float*)d_in[23];

  float* out      = (float*)d_out;
  float* xn_last  = out + (size_t)BB * TT * DD;
  float* aa_out   = xn_last + BB * DD;
  float* bb_out   = aa_out + BB * DD;
  float* pp_out   = bb_out + BB * DD;
  float* xn2_last = pp_out + BB * DD;
  float* x1 = out;  // x1 lives in the out buffer

  char* ws = (char*)d_ws;
  const size_t MB = 1024ull * 1024ull;
  u16* WT4   = (u16*)(ws + 0 * MB);     // Wk,Wv,Wr,Wo transposed bf16, 2MB each
  u16* WkT   = WT4;
  u16* WoT   = WT4 + 3u * 1024 * 1024;
  u16* CkCrT = (u16*)(ws + 8 * MB);     // [5120,1024] bf16 = 10MB (Ck rows 0..4095, Cr rows 4096..5119)
  u16* CrTd  = CkCrT + (size_t)4096 * 1024;
  u16* CvT   = (u16*)(ws + 18 * MB);    // 8MB  [1024,4096]
  u16* xk    = (u16*)(ws + 26 * MB);    // 16MB each, contiguous for batched QKV A
  u16* xv    = (u16*)(ws + 42 * MB);
  u16* xr    = (u16*)(ws + 58 * MB);
  u16* kbuf  = (u16*)(ws + 74 * MB);    // 16MB bf16 each, contiguous for batched QKV C
  u16* vbuf  = (u16*)(ws + 90 * MB);
  u16* sigr  = (u16*)(ws + 106 * MB);
  float* sab = (float*)(ws + 122 * MB); // 1MB each
  float* sbb = (float*)(ws + 123 * MB);
  float* psb = (float*)(ws + 124 * MB);
  float* pab = (float*)(ws + 125 * MB);
  float* pbb = (float*)(ws + 126 * MB);
  float* ppb = (float*)(ws + 127 * MB);
  // reuse (lifetimes disjoint):
  u16* rmb   = (u16*)(ws + 26 * MB);    // over xk (dead after QKV GEMM)
  u16* xk2   = (u16*)(ws + 26 * MB);    // over rmb (dead after Wo GEMM)
  u16* xr2   = (u16*)(ws + 42 * MB);    // over xv
  u16* sigr2 = (u16*)(ws + 58 * MB);    // over xr
  u16* kc    = (u16*)(ws + 74 * MB);    // 64MB over kbuf/vbuf/sigr/s* (all dead after chunk_out)

  dim3 tb32(32, 8);
  transpose5_bf16<<<dim3(32, 32, 5), tb32, 0, stream>>>(Wk, Wv, Wr, Wo, Cr, WT4, CrTd);
  transpose_bf16<<<dim3(128, 32), tb32, 0, stream>>>(Ck, CkCrT, 1024, 4096);
  transpose_bf16<<<dim3(32, 128), tb32, 0, stream>>>(Cv, CvT, 4096, 1024);

  ln1mix_kernel<<<MM, 256, 0, stream>>>(x, attx, ln1g, ln1b, mk, mv, mr, xk, xv, xr, xn_last);

  // batched QKV: z=0 -> kbuf (bf16), z=1 -> vbuf (bf16), z=2 -> sigr (sigmoid bf16)
  gemm_bt<5><<<dim3(8, 64, 3), 256, 0, stream>>>(xk, nullptr, WkT, nullptr, nullptr,
                                                 kbuf, nullptr, MM, 1024, 1024);

  wkv_chunk_sum<<<NCHAN * NCH / 256, 256, 0, stream>>>(kbuf, vbuf, decay, sab, sbb, psb);
  wkv_chunk_scan<<<NCHAN / 256, 256, 0, stream>>>(sab, sbb, psb, decay, aa0, bb0, pp0,
                                                  pab, pbb, ppb, aa_out, bb_out, pp_out);
  wkv_chunk_out<<<NCHAN * NCH / 256, 256, 0, stream>>>(kbuf, vbuf, sigr, decay, first,
                                                       pab, pbb, ppb, rmb);

  gemm_bt<3><<<dim3(8, 64), 256, 0, stream>>>(rmb, nullptr, WoT, x, nullptr,
                                              x1, nullptr, MM, 1024, 1024);

  ln2mix_kernel<<<MM, 256, 0, stream>>>(x1, ffnx, ln2g, ln2b, cmk, cmr, xk2, xr2, xn2_last);

  // merged FFN [Ck|Cr]: bx<32 uses xk2 -> kc (relu^2), bx>=32 uses xr2 -> sigr2 (sigmoid)
  gemm_bt<6><<<dim3(40, 64), 256, 0, stream>>>(xk2, xr2, CkCrT, nullptr, nullptr,
                                               kc, sigr2, MM, 5120, 1024);

  gemm_bt<4><<<dim3(8, 64), 256, 0, stream>>>(kc, nullptr, CvT, x1, sigr2,
                                              out, nullptr, MM, 1024, 4096);
}